// Round 2
// baseline (779.625 us; speedup 1.0000x reference)
//
#include <hip/hip_runtime.h>
#include <hip/hip_bf16.h>

#define NB 16
#define VOX 884736        // 96*96*96
#define NPTS 4096
#define CHUNK 1024
#define NCHUNK 864        // VOX / CHUNK

typedef _Float16 f16x8 __attribute__((ext_vector_type(8)));
typedef _Float16 f16x4 __attribute__((ext_vector_type(4)));
typedef float f32x4 __attribute__((ext_vector_type(4)));

// ---------------- point extraction (unchanged, verified) ----------------

__global__ __launch_bounds__(256) void count_kernel(const float* __restrict__ vol,
                                                    int* __restrict__ counts) {
    int blk = blockIdx.x;  // b*NCHUNK + c
    const float4* v4 = (const float4*)(vol + (size_t)blk * CHUNK);
    float4 v = v4[threadIdx.x];
    int cnt = (v.x > 0.5f) + (v.y > 0.5f) + (v.z > 0.5f) + (v.w > 0.5f);
    for (int off = 32; off; off >>= 1) cnt += __shfl_down(cnt, off, 64);
    __shared__ int s[4];
    if ((threadIdx.x & 63) == 0) s[threadIdx.x >> 6] = cnt;
    __syncthreads();
    if (threadIdx.x == 0) counts[blk] = s[0] + s[1] + s[2] + s[3];
}

__global__ __launch_bounds__(1024) void scan_kernel(const int* __restrict__ counts,
                                                    int* __restrict__ prefix,
                                                    int* __restrict__ totals) {
    __shared__ int s[1024];
    int b = blockIdx.x, t = threadIdx.x;
    int v = (t < NCHUNK) ? counts[b * NCHUNK + t] : 0;
    s[t] = v;
    __syncthreads();
    for (int off = 1; off < 1024; off <<= 1) {
        int x = (t >= off) ? s[t - off] : 0;
        __syncthreads();
        s[t] += x;
        __syncthreads();
    }
    if (t < NCHUNK) prefix[b * NCHUNK + t] = s[t] - v;   // exclusive
    if (t == NCHUNK - 1) totals[b] = s[t];
}

__global__ __launch_bounds__(256) void points_kernel(const float* __restrict__ vol,
                                                     const int* __restrict__ prefix,
                                                     const int* __restrict__ totals,
                                                     float* __restrict__ pts) {
    int gid = blockIdx.x * 256 + threadIdx.x;  // 0 .. NB*NPTS
    int b = gid >> 12;
    int p = gid & (NPTS - 1);
    int n = totals[b];
    float px = 0.f, py = 0.f, pz = 0.f;
    if (n > 0) {
        int k;
        if (n >= NPTS) {
            float t = (float)p * ((float)n - 1.0f);
            t = t / 4095.0f;
            k = (int)t;
            if (k > n - 1) k = n - 1;
            if (k < 0) k = 0;
        } else {
            k = p % n;
        }
        const int* pref = prefix + b * NCHUNK;
        int lo = 0, hi = NCHUNK - 1;
        while (lo < hi) {
            int mid = (lo + hi + 1) >> 1;
            if (pref[mid] <= k) lo = mid; else hi = mid - 1;
        }
        int r = k - pref[lo];
        const float4* v4 = (const float4*)(vol + (size_t)b * VOX + (size_t)lo * CHUNK);
        int flat = 0, acc = 0;
        for (int i = 0; i < CHUNK / 4; i++) {
            float4 q = v4[i];
            int c0 = q.x > 0.5f, c1 = q.y > 0.5f, c2 = q.z > 0.5f, c3 = q.w > 0.5f;
            int s4 = c0 + c1 + c2 + c3;
            if (acc + s4 > r) {
                int rr = r - acc;
                int j;
                if (c0 && rr == 0) j = 0;
                else {
                    rr -= c0;
                    if (c1 && rr == 0) j = 1;
                    else {
                        rr -= c1;
                        if (c2 && rr == 0) j = 2; else j = 3;
                    }
                }
                flat = lo * CHUNK + i * 4 + j;
                break;
            }
            acc += s4;
        }
        int dd = flat / 9216;           // 96*96
        int rem = flat - dd * 9216;
        int hh = rem / 96;
        int ww = rem - hh * 96;
        px = (float)dd / 95.0f * 2.0f - 1.0f;
        py = (float)hh / 95.0f * 2.0f - 1.0f;
        pz = (float)ww / 95.0f * 2.0f - 1.0f;
    }
    pts[((size_t)b * 3 + 0) * NPTS + p] = px;
    pts[((size_t)b * 3 + 1) * NPTS + p] = py;
    pts[((size_t)b * 3 + 2) * NPTS + p] = pz;
}

// ---------------- weight cast fp32 -> fp16 ----------------

__global__ __launch_bounds__(256) void cast_w(const float* __restrict__ wf,
                                              _Float16* __restrict__ wh, int n) {
    int i = blockIdx.x * 256 + threadIdx.x;
    if (i < n) wh[i] = (_Float16)wf[i];
}

// ---------------- layer 1 (C=3 -> 64), output y[b][p][64] fp32 ----------------

__global__ __launch_bounds__(256) void conv1_kernel(const float* __restrict__ pts,
                                                    const float* __restrict__ w1,
                                                    float* __restrict__ y) {
    int gid = blockIdx.x * 4 + (threadIdx.x >> 6);   // point id
    int b = gid >> 12;
    int p = gid & (NPTS - 1);
    int o = threadIdx.x & 63;
    float x0 = pts[((size_t)b * 3 + 0) * NPTS + p];
    float x1 = pts[((size_t)b * 3 + 1) * NPTS + p];
    float x2 = pts[((size_t)b * 3 + 2) * NPTS + p];
    float acc = w1[o * 3 + 0] * x0 + w1[o * 3 + 1] * x1 + w1[o * 3 + 2] * x2;
    y[((size_t)(b * NPTS + p)) * 64 + o] = acc;
}

// ---------------- MFMA GEMM: y[b][p][o] = sum_c x[b][p][c] * w[o][c] ----------------
// A-frag: lane l holds X[p0 + pf*16 + (l&15)][c0 + (l>>4)*8 + j]   (8 contiguous halves)
// B-frag: lane l holds W[o0 + of*16 + (l&15)][c0 + (l>>4)*8 + j]   (8 contiguous halves)
// D:      lane l, reg j -> D[p = (l>>4)*4 + j][o = l&15]

template <int CIN, int COUT>
__global__ __launch_bounds__(256) void mfma_gemm(const _Float16* __restrict__ x,
                                                 const _Float16* __restrict__ w,
                                                 float* __restrict__ y) {
    int b = blockIdx.z;
    int p0 = blockIdx.x * 256 + (threadIdx.x >> 6) * 64;
    int o0 = blockIdx.y * 64;
    int lane = threadIdx.x & 63;
    int lr = lane & 15;
    int lk = lane >> 4;
    const _Float16* xb = x + ((size_t)(b * NPTS) + p0) * CIN;
    const _Float16* wb = w + (size_t)o0 * CIN;
    f32x4 acc[4][4] = {};
    #pragma unroll 2
    for (int c0 = 0; c0 < CIN; c0 += 32) {
        f16x8 af[4], bf[4];
        #pragma unroll
        for (int i = 0; i < 4; i++)
            af[i] = *(const f16x8*)(xb + (size_t)(i * 16 + lr) * CIN + c0 + lk * 8);
        #pragma unroll
        for (int i = 0; i < 4; i++)
            bf[i] = *(const f16x8*)(wb + (size_t)(i * 16 + lr) * CIN + c0 + lk * 8);
        #pragma unroll
        for (int pf = 0; pf < 4; pf++)
            #pragma unroll
            for (int of = 0; of < 4; of++)
                acc[pf][of] = __builtin_amdgcn_mfma_f32_16x16x32_f16(af[pf], bf[of], acc[pf][of], 0, 0, 0);
    }
    float* yb = y + ((size_t)(b * NPTS) + p0) * COUT + o0;
    #pragma unroll
    for (int pf = 0; pf < 4; pf++)
        #pragma unroll
        for (int of = 0; of < 4; of++)
            #pragma unroll
            for (int j = 0; j < 4; j++)
                yb[(size_t)(pf * 16 + lk * 4 + j) * COUT + of * 16 + lr] = acc[pf][of][j];
}

// ---------------- GroupNorm stats over y[b][p][C] fp32 ----------------

template <int C>
__global__ __launch_bounds__(256) void gn_stats_t(const float* __restrict__ y,
                                                  float* __restrict__ stats) {
    constexpr int GS = C / 8;          // channels per group
    constexpr int R = 256 / GS;        // p-rows per iteration
    int b = blockIdx.x >> 3;
    int g = blockIdx.x & 7;
    int cl = threadIdx.x % GS;
    int pr = threadIdx.x / GS;
    const float* base = y + (size_t)(b * NPTS) * C + g * GS + cl;
    float sum = 0.f, sq = 0.f;
    for (int p = pr; p < NPTS; p += R) {
        float v = base[(size_t)p * C];
        sum += v;
        sq += v * v;
    }
    for (int off = 32; off; off >>= 1) {
        sum += __shfl_down(sum, off, 64);
        sq += __shfl_down(sq, off, 64);
    }
    __shared__ float ss[8];
    if ((threadIdx.x & 63) == 0) {
        ss[(threadIdx.x >> 6) * 2] = sum;
        ss[(threadIdx.x >> 6) * 2 + 1] = sq;
    }
    __syncthreads();
    if (threadIdx.x == 0) {
        float S = 0.f, Q = 0.f;
        for (int wv = 0; wv < 4; wv++) { S += ss[wv * 2]; Q += ss[wv * 2 + 1]; }
        float inv = 1.0f / (float)(GS * NPTS);
        float mu = S * inv;
        float var = Q * inv - mu * mu;
        if (var < 0.f) var = 0.f;
        float rstd = rsqrtf(var + 1e-5f);
        stats[(b * 8 + g) * 2] = mu;
        stats[(b * 8 + g) * 2 + 1] = rstd;
    }
}

// ---------------- GN normalize + ReLU + cast: y fp32 [b][p][C] -> x fp16 ----------------

template <int C>
__global__ __launch_bounds__(256) void gn_norm_relu_t(const float* __restrict__ y,
                                                      const float* __restrict__ stats,
                                                      const float* __restrict__ gamma,
                                                      const float* __restrict__ beta,
                                                      _Float16* __restrict__ x) {
    int i4 = blockIdx.x * 256 + threadIdx.x;          // float4 index
    constexpr int C4 = C / 4;
    int c = (i4 % C4) * 4;
    int row = i4 / C4;                                // b*NPTS + p
    int b = row >> 12;
    int g = c / (C / 8);
    float mu = stats[(b * 8 + g) * 2];
    float rstd = stats[(b * 8 + g) * 2 + 1];
    float4 ga4 = *(const float4*)(gamma + c);
    float4 be4 = *(const float4*)(beta + c);
    float4 v = ((const float4*)y)[i4];
    f16x4 o;
    o[0] = (_Float16)fmaxf((v.x - mu) * rstd * ga4.x + be4.x, 0.f);
    o[1] = (_Float16)fmaxf((v.y - mu) * rstd * ga4.y + be4.y, 0.f);
    o[2] = (_Float16)fmaxf((v.z - mu) * rstd * ga4.z + be4.z, 0.f);
    o[3] = (_Float16)fmaxf((v.w - mu) * rstd * ga4.w + be4.w, 0.f);
    *(f16x4*)(x + (size_t)i4 * 4) = o;
}

// ---------------- layer-4: GN+ReLU+maxpool over p, y4 [b][p][512] ----------------

__global__ __launch_bounds__(256) void pool4a(const float* __restrict__ y,
                                              const float* __restrict__ stats,
                                              const float* __restrict__ gamma,
                                              const float* __restrict__ beta,
                                              float* __restrict__ partial) {
    int b = blockIdx.x >> 4;
    int pc = blockIdx.x & 15;          // 16 chunks of 256 points
    int o = threadIdx.x;               // channel o and o+256
    int g0 = o >> 6, g1 = (o + 256) >> 6;
    float mu0 = stats[(b * 8 + g0) * 2], rs0 = stats[(b * 8 + g0) * 2 + 1];
    float mu1 = stats[(b * 8 + g1) * 2], rs1 = stats[(b * 8 + g1) * 2 + 1];
    float ga0 = gamma[o] * rs0, be0 = beta[o] - mu0 * ga0;
    float ga1 = gamma[o + 256] * rs1, be1 = beta[o + 256] - mu1 * ga1;
    const float* yb = y + ((size_t)(b * NPTS) + pc * 256) * 512;
    float m0 = -1e30f, m1 = -1e30f;
    for (int p = 0; p < 256; p++) {
        m0 = fmaxf(m0, yb[(size_t)p * 512 + o] * ga0 + be0);
        m1 = fmaxf(m1, yb[(size_t)p * 512 + o + 256] * ga1 + be1);
    }
    partial[(size_t)(b * 16 + pc) * 512 + o] = m0;
    partial[(size_t)(b * 16 + pc) * 512 + o + 256] = m1;
}

__global__ __launch_bounds__(256) void pool4b(const float* __restrict__ partial,
                                              float* __restrict__ g) {
    int b = blockIdx.x;
    int o = threadIdx.x;
    float m0 = -1e30f, m1 = -1e30f;
    for (int pc = 0; pc < 16; pc++) {
        m0 = fmaxf(m0, partial[(size_t)(b * 16 + pc) * 512 + o]);
        m1 = fmaxf(m1, partial[(size_t)(b * 16 + pc) * 512 + o + 256]);
    }
    g[b * 512 + o] = fmaxf(m0, 0.f);
    g[b * 512 + o + 256] = fmaxf(m1, 0.f);
}

// ---------------- FC head ----------------

__global__ __launch_bounds__(128) void head_kernel(const float* __restrict__ g,
                                                   const float* __restrict__ fc1w,
                                                   const float* __restrict__ fc1b,
                                                   const float* __restrict__ fc2w,
                                                   const float* __restrict__ fc2b,
                                                   float* __restrict__ out) {
    int b = blockIdx.x;
    int o = threadIdx.x;   // 128
    __shared__ float sg[512];
    for (int i = threadIdx.x; i < 512; i += 128) sg[i] = g[b * 512 + i];
    __syncthreads();
    float acc = fc1b[o];
    for (int c = 0; c < 512; c++) acc += sg[c] * fc1w[o * 512 + c];
    float h = fmaxf(acc, 0.f) * fc2w[o];
    for (int off = 32; off; off >>= 1) h += __shfl_down(h, off, 64);
    __shared__ float s2[2];
    if ((threadIdx.x & 63) == 0) s2[threadIdx.x >> 6] = h;
    __syncthreads();
    if (threadIdx.x == 0) out[b] = s2[0] + s2[1] + fc2b[0];
}

// ---------------- launch ----------------

extern "C" void kernel_launch(void* const* d_in, const int* in_sizes, int n_in,
                              void* d_out, int out_size, void* d_ws, size_t ws_size,
                              hipStream_t stream) {
    const float* vol  = (const float*)d_in[0];
    const float* w1   = (const float*)d_in[1];
    const float* gn1w = (const float*)d_in[2];
    const float* gn1b = (const float*)d_in[3];
    const float* w2   = (const float*)d_in[4];
    const float* gn2w = (const float*)d_in[5];
    const float* gn2b = (const float*)d_in[6];
    const float* w3   = (const float*)d_in[7];
    const float* gn3w = (const float*)d_in[8];
    const float* gn3b = (const float*)d_in[9];
    const float* w4   = (const float*)d_in[10];
    const float* gn4w = (const float*)d_in[11];
    const float* gn4b = (const float*)d_in[12];
    const float* fc1w = (const float*)d_in[13];
    const float* fc1b = (const float*)d_in[14];
    const float* fc2w = (const float*)d_in[15];
    const float* fc2b = (const float*)d_in[16];
    float* out = (float*)d_out;

    char* ws = (char*)d_ws;
    size_t cur = 0;
    auto alloc = [&](size_t bytes) -> void* {
        cur = (cur + 255) & ~(size_t)255;
        void* p = ws + cur;
        cur += bytes;
        return p;
    };
    int*      counts  = (int*)alloc((size_t)NB * NCHUNK * 4);
    int*      prefix  = (int*)alloc((size_t)NB * NCHUNK * 4);
    int*      totals  = (int*)alloc(64);
    float*    stats   = (float*)alloc((size_t)NB * 8 * 2 * 4);
    float*    pts     = (float*)alloc((size_t)NB * 3 * NPTS * 4);
    float*    gbuf    = (float*)alloc((size_t)NB * 512 * 4);
    float*    partial = (float*)alloc((size_t)NB * 16 * 512 * 4);
    _Float16* w2h     = (_Float16*)alloc((size_t)128 * 64 * 2);
    _Float16* w3h     = (_Float16*)alloc((size_t)256 * 128 * 2);
    _Float16* w4h     = (_Float16*)alloc((size_t)512 * 256 * 2);
    _Float16* xbuf    = (_Float16*)alloc((size_t)NB * NPTS * 256 * 2);   // fp16 activations
    float*    ybuf    = (float*)alloc((size_t)NB * NPTS * 512 * 4);      // fp32 pre-norm

    // 1. points
    count_kernel<<<dim3(NB * NCHUNK), dim3(256), 0, stream>>>(vol, counts);
    scan_kernel<<<dim3(NB), dim3(1024), 0, stream>>>(counts, prefix, totals);
    points_kernel<<<dim3(NB * NPTS / 256), dim3(256), 0, stream>>>(vol, prefix, totals, pts);

    // 2. weight casts
    cast_w<<<dim3((128 * 64 + 255) / 256), dim3(256), 0, stream>>>(w2, w2h, 128 * 64);
    cast_w<<<dim3((256 * 128 + 255) / 256), dim3(256), 0, stream>>>(w3, w3h, 256 * 128);
    cast_w<<<dim3((512 * 256 + 255) / 256), dim3(256), 0, stream>>>(w4, w4h, 512 * 256);

    // 3. layer 1: 3 -> 64
    conv1_kernel<<<dim3(NB * NPTS / 4), dim3(256), 0, stream>>>(pts, w1, ybuf);
    gn_stats_t<64><<<dim3(NB * 8), dim3(256), 0, stream>>>(ybuf, stats);
    gn_norm_relu_t<64><<<dim3(NB * NPTS * 64 / 4 / 256), dim3(256), 0, stream>>>(ybuf, stats, gn1w, gn1b, xbuf);

    // 4. layer 2: 64 -> 128
    mfma_gemm<64, 128><<<dim3(16, 2, NB), dim3(256), 0, stream>>>(xbuf, w2h, ybuf);
    gn_stats_t<128><<<dim3(NB * 8), dim3(256), 0, stream>>>(ybuf, stats);
    gn_norm_relu_t<128><<<dim3(NB * NPTS * 128 / 4 / 256), dim3(256), 0, stream>>>(ybuf, stats, gn2w, gn2b, xbuf);

    // 5. layer 3: 128 -> 256
    mfma_gemm<128, 256><<<dim3(16, 4, NB), dim3(256), 0, stream>>>(xbuf, w3h, ybuf);
    gn_stats_t<256><<<dim3(NB * 8), dim3(256), 0, stream>>>(ybuf, stats);
    gn_norm_relu_t<256><<<dim3(NB * NPTS * 256 / 4 / 256), dim3(256), 0, stream>>>(ybuf, stats, gn3w, gn3b, xbuf);

    // 6. layer 4: 256 -> 512, then GN stats + fused norm/relu/maxpool
    mfma_gemm<256, 512><<<dim3(16, 8, NB), dim3(256), 0, stream>>>(xbuf, w4h, ybuf);
    gn_stats_t<512><<<dim3(NB * 8), dim3(256), 0, stream>>>(ybuf, stats);
    pool4a<<<dim3(NB * 16), dim3(256), 0, stream>>>(ybuf, stats, gn4w, gn4b, partial);
    pool4b<<<dim3(NB), dim3(256), 0, stream>>>(partial, gbuf);

    // 7. head
    head_kernel<<<dim3(NB), dim3(128), 0, stream>>>(gbuf, fc1w, fc1b, fc2w, fc2b, out);
}

// Round 3
// 296.515 us; speedup vs baseline: 2.6293x; 2.6293x over previous
//
#include <hip/hip_runtime.h>
#include <hip/hip_bf16.h>

#define NB 16
#define VOX 884736        // 96*96*96
#define NPTS 4096
#define CHUNK 1024
#define NCHUNK 864        // VOX / CHUNK

typedef _Float16 f16x8 __attribute__((ext_vector_type(8)));
typedef _Float16 f16x4 __attribute__((ext_vector_type(4)));
typedef float f32x4 __attribute__((ext_vector_type(4)));

// ---------------- point extraction (unchanged, verified) ----------------

__global__ __launch_bounds__(256) void count_kernel(const float* __restrict__ vol,
                                                    int* __restrict__ counts) {
    int blk = blockIdx.x;  // b*NCHUNK + c
    const float4* v4 = (const float4*)(vol + (size_t)blk * CHUNK);
    float4 v = v4[threadIdx.x];
    int cnt = (v.x > 0.5f) + (v.y > 0.5f) + (v.z > 0.5f) + (v.w > 0.5f);
    for (int off = 32; off; off >>= 1) cnt += __shfl_down(cnt, off, 64);
    __shared__ int s[4];
    if ((threadIdx.x & 63) == 0) s[threadIdx.x >> 6] = cnt;
    __syncthreads();
    if (threadIdx.x == 0) counts[blk] = s[0] + s[1] + s[2] + s[3];
}

__global__ __launch_bounds__(1024) void scan_kernel(const int* __restrict__ counts,
                                                    int* __restrict__ prefix,
                                                    int* __restrict__ totals) {
    __shared__ int s[1024];
    int b = blockIdx.x, t = threadIdx.x;
    int v = (t < NCHUNK) ? counts[b * NCHUNK + t] : 0;
    s[t] = v;
    __syncthreads();
    for (int off = 1; off < 1024; off <<= 1) {
        int x = (t >= off) ? s[t - off] : 0;
        __syncthreads();
        s[t] += x;
        __syncthreads();
    }
    if (t < NCHUNK) prefix[b * NCHUNK + t] = s[t] - v;   // exclusive
    if (t == NCHUNK - 1) totals[b] = s[t];
}

__global__ __launch_bounds__(256) void points_kernel(const float* __restrict__ vol,
                                                     const int* __restrict__ prefix,
                                                     const int* __restrict__ totals,
                                                     float* __restrict__ pts) {
    int gid = blockIdx.x * 256 + threadIdx.x;  // 0 .. NB*NPTS
    int b = gid >> 12;
    int p = gid & (NPTS - 1);
    int n = totals[b];
    float px = 0.f, py = 0.f, pz = 0.f;
    if (n > 0) {
        int k;
        if (n >= NPTS) {
            float t = (float)p * ((float)n - 1.0f);
            t = t / 4095.0f;
            k = (int)t;
            if (k > n - 1) k = n - 1;
            if (k < 0) k = 0;
        } else {
            k = p % n;
        }
        const int* pref = prefix + b * NCHUNK;
        int lo = 0, hi = NCHUNK - 1;
        while (lo < hi) {
            int mid = (lo + hi + 1) >> 1;
            if (pref[mid] <= k) lo = mid; else hi = mid - 1;
        }
        int r = k - pref[lo];
        const float4* v4 = (const float4*)(vol + (size_t)b * VOX + (size_t)lo * CHUNK);
        int flat = 0, acc = 0;
        for (int i = 0; i < CHUNK / 4; i++) {
            float4 q = v4[i];
            int c0 = q.x > 0.5f, c1 = q.y > 0.5f, c2 = q.z > 0.5f, c3 = q.w > 0.5f;
            int s4 = c0 + c1 + c2 + c3;
            if (acc + s4 > r) {
                int rr = r - acc;
                int j;
                if (c0 && rr == 0) j = 0;
                else {
                    rr -= c0;
                    if (c1 && rr == 0) j = 1;
                    else {
                        rr -= c1;
                        if (c2 && rr == 0) j = 2; else j = 3;
                    }
                }
                flat = lo * CHUNK + i * 4 + j;
                break;
            }
            acc += s4;
        }
        int dd = flat / 9216;           // 96*96
        int rem = flat - dd * 9216;
        int hh = rem / 96;
        int ww = rem - hh * 96;
        px = (float)dd / 95.0f * 2.0f - 1.0f;
        py = (float)hh / 95.0f * 2.0f - 1.0f;
        pz = (float)ww / 95.0f * 2.0f - 1.0f;
    }
    pts[((size_t)b * 3 + 0) * NPTS + p] = px;
    pts[((size_t)b * 3 + 1) * NPTS + p] = py;
    pts[((size_t)b * 3 + 2) * NPTS + p] = pz;
}

// ---------------- weight cast fp32 -> fp16 ----------------

__global__ __launch_bounds__(256) void cast_w(const float* __restrict__ wf,
                                              _Float16* __restrict__ wh, int n) {
    int i = blockIdx.x * 256 + threadIdx.x;
    if (i < n) wh[i] = (_Float16)wf[i];
}

// ---------------- layer 1 (3 -> 64) with fused partial GN stats ----------------
// y[b][p][64] fp32 ; pstat1[b][8 groups][16 pchunks][2]

__global__ __launch_bounds__(256) void conv1_kernel(const float* __restrict__ pts,
                                                    const float* __restrict__ w1,
                                                    float* __restrict__ y,
                                                    float* __restrict__ pstat1) {
    int b = blockIdx.x >> 4;
    int pc = blockIdx.x & 15;
    int p = pc * 256 + threadIdx.x;
    float x0 = pts[((size_t)b * 3 + 0) * NPTS + p];
    float x1 = pts[((size_t)b * 3 + 1) * NPTS + p];
    float x2 = pts[((size_t)b * 3 + 2) * NPTS + p];
    float yv[64];
    float s[8] = {}, q[8] = {};
    #pragma unroll
    for (int o = 0; o < 64; o++) {
        float a = w1[o * 3 + 0] * x0 + w1[o * 3 + 1] * x1 + w1[o * 3 + 2] * x2;
        yv[o] = a;
        s[o >> 3] += a;
        q[o >> 3] += a * a;
    }
    float4* dst = (float4*)(y + ((size_t)(b * NPTS) + p) * 64);
    #pragma unroll
    for (int i = 0; i < 16; i++)
        dst[i] = make_float4(yv[i * 4], yv[i * 4 + 1], yv[i * 4 + 2], yv[i * 4 + 3]);
    // block-reduce the 8 per-group partials
    __shared__ float red[4][8][2];
    int wv = threadIdx.x >> 6;
    #pragma unroll
    for (int g = 0; g < 8; g++) {
        float S = s[g], Q = q[g];
        for (int off = 32; off; off >>= 1) {
            S += __shfl_down(S, off, 64);
            Q += __shfl_down(Q, off, 64);
        }
        if ((threadIdx.x & 63) == 0) { red[wv][g][0] = S; red[wv][g][1] = Q; }
    }
    __syncthreads();
    if (threadIdx.x < 8) {
        int g = threadIdx.x;
        float S = red[0][g][0] + red[1][g][0] + red[2][g][0] + red[3][g][0];
        float Q = red[0][g][1] + red[1][g][1] + red[2][g][1] + red[3][g][1];
        float* d = pstat1 + (((size_t)(b * 8 + g)) * 16 + pc) * 2;
        d[0] = S; d[1] = Q;
    }
}

__global__ __launch_bounds__(64) void gn_finalize1(const float* __restrict__ pstat,
                                                   const float* __restrict__ gamma,
                                                   const float* __restrict__ beta,
                                                   float* __restrict__ scale,
                                                   float* __restrict__ shift) {
    int b = blockIdx.x >> 3, g = blockIdx.x & 7;
    const float* base = pstat + (size_t)(b * 8 + g) * 32;
    float S = 0.f, Q = 0.f;
    if (threadIdx.x < 16) { S = base[threadIdx.x * 2]; Q = base[threadIdx.x * 2 + 1]; }
    for (int off = 8; off; off >>= 1) {
        S += __shfl_down(S, off, 64);
        Q += __shfl_down(Q, off, 64);
    }
    __shared__ float ms[2];
    if (threadIdx.x == 0) {
        float inv = 1.0f / (8.0f * 4096.0f);
        float mu = S * inv;
        float var = Q * inv - mu * mu;
        if (var < 0.f) var = 0.f;
        ms[0] = mu; ms[1] = rsqrtf(var + 1e-5f);
    }
    __syncthreads();
    if (threadIdx.x < 8) {
        int c = g * 8 + threadIdx.x;
        float ga = gamma[c] * ms[1];
        scale[b * 64 + c] = ga;
        shift[b * 64 + c] = beta[c] - ms[0] * ga;
    }
}

// ---------------- MFMA GEMM with fused partial GN stats ----------------
// y[b][p][o] = sum_c x[b][p][c]*w[o][c] ; pstat[b][COUT][16 pblocks][2]

template <int CIN, int COUT>
__global__ __launch_bounds__(256) void mfma_gemm(const _Float16* __restrict__ x,
                                                 const _Float16* __restrict__ w,
                                                 float* __restrict__ y,
                                                 float* __restrict__ pstat) {
    int b = blockIdx.z;
    int p0 = blockIdx.x * 256 + (threadIdx.x >> 6) * 64;
    int o0 = blockIdx.y * 64;
    int lane = threadIdx.x & 63;
    int lr = lane & 15;
    int lk = lane >> 4;
    const _Float16* xb = x + ((size_t)(b * NPTS) + p0) * CIN;
    const _Float16* wb = w + (size_t)o0 * CIN;
    f32x4 acc[4][4] = {};
    #pragma unroll 2
    for (int c0 = 0; c0 < CIN; c0 += 32) {
        f16x8 af[4], bf[4];
        #pragma unroll
        for (int i = 0; i < 4; i++)
            af[i] = *(const f16x8*)(xb + (size_t)(i * 16 + lr) * CIN + c0 + lk * 8);
        #pragma unroll
        for (int i = 0; i < 4; i++)
            bf[i] = *(const f16x8*)(wb + (size_t)(i * 16 + lr) * CIN + c0 + lk * 8);
        #pragma unroll
        for (int pf = 0; pf < 4; pf++)
            #pragma unroll
            for (int of = 0; of < 4; of++)
                acc[pf][of] = __builtin_amdgcn_mfma_f32_16x16x32_f16(af[pf], bf[of], acc[pf][of], 0, 0, 0);
    }
    float* yb = y + ((size_t)(b * NPTS) + p0) * COUT + o0;
    #pragma unroll
    for (int pf = 0; pf < 4; pf++)
        #pragma unroll
        for (int of = 0; of < 4; of++)
            #pragma unroll
            for (int j = 0; j < 4; j++)
                yb[(size_t)(pf * 16 + lk * 4 + j) * COUT + of * 16 + lr] = acc[pf][of][j];
    // fused partial stats: per-o (sum, sumsq) over this block's 256 p
    __shared__ float sred[4][64][2];
    int wv = threadIdx.x >> 6;
    #pragma unroll
    for (int of = 0; of < 4; of++) {
        float S = 0.f, Q = 0.f;
        #pragma unroll
        for (int pf = 0; pf < 4; pf++)
            #pragma unroll
            for (int j = 0; j < 4; j++) {
                float v = acc[pf][of][j];
                S += v; Q += v * v;
            }
        S += __shfl_xor(S, 16, 64); Q += __shfl_xor(Q, 16, 64);
        S += __shfl_xor(S, 32, 64); Q += __shfl_xor(Q, 32, 64);
        if (lk == 0) { sred[wv][of * 16 + lr][0] = S; sred[wv][of * 16 + lr][1] = Q; }
    }
    __syncthreads();
    if (threadIdx.x < 64) {
        int o = threadIdx.x;
        float S = sred[0][o][0] + sred[1][o][0] + sred[2][o][0] + sred[3][o][0];
        float Q = sred[0][o][1] + sred[1][o][1] + sred[2][o][1] + sred[3][o][1];
        float* d = pstat + (((size_t)b * COUT + o0 + o) * 16 + blockIdx.x) * 2;
        d[0] = S; d[1] = Q;
    }
}

// ---------------- GN finalize for GEMM layers: pstat -> scale/shift ----------------

template <int C>
__global__ __launch_bounds__(256) void gn_finalizeG(const float* __restrict__ pstat,
                                                    const float* __restrict__ gamma,
                                                    const float* __restrict__ beta,
                                                    float* __restrict__ scale,
                                                    float* __restrict__ shift) {
    constexpr int GS = C / 8;
    int b = blockIdx.x >> 3, g = blockIdx.x & 7;
    const float* base = pstat + ((size_t)b * C + g * GS) * 32;
    float S = 0.f, Q = 0.f;
    for (int i = threadIdx.x; i < GS * 16; i += 256) { S += base[2 * i]; Q += base[2 * i + 1]; }
    for (int off = 32; off; off >>= 1) {
        S += __shfl_down(S, off, 64);
        Q += __shfl_down(Q, off, 64);
    }
    __shared__ float ss[8];
    if ((threadIdx.x & 63) == 0) {
        ss[(threadIdx.x >> 6) * 2] = S;
        ss[(threadIdx.x >> 6) * 2 + 1] = Q;
    }
    __syncthreads();
    __shared__ float ms[2];
    if (threadIdx.x == 0) {
        float St = ss[0] + ss[2] + ss[4] + ss[6];
        float Qt = ss[1] + ss[3] + ss[5] + ss[7];
        float inv = 1.0f / ((float)GS * 4096.0f);
        float mu = St * inv;
        float var = Qt * inv - mu * mu;
        if (var < 0.f) var = 0.f;
        ms[0] = mu; ms[1] = rsqrtf(var + 1e-5f);
    }
    __syncthreads();
    for (int i = threadIdx.x; i < GS; i += 256) {
        int c = g * GS + i;
        float ga = gamma[c] * ms[1];
        scale[(size_t)b * C + c] = ga;
        shift[(size_t)b * C + c] = beta[c] - ms[0] * ga;
    }
}

// ---------------- GN normalize + ReLU + cast fp16 ----------------

template <int C>
__global__ __launch_bounds__(256) void gn_norm_relu_t(const float* __restrict__ y,
                                                      const float* __restrict__ scale,
                                                      const float* __restrict__ shift,
                                                      _Float16* __restrict__ x) {
    int i4 = blockIdx.x * 256 + threadIdx.x;          // float4 index
    constexpr int C4 = C / 4;
    int c = (i4 % C4) * 4;
    int b = (i4 / C4) >> 12;
    float4 sc = *(const float4*)(scale + (size_t)b * C + c);
    float4 sh = *(const float4*)(shift + (size_t)b * C + c);
    float4 v = ((const float4*)y)[i4];
    f16x4 o;
    o[0] = (_Float16)fmaxf(v.x * sc.x + sh.x, 0.f);
    o[1] = (_Float16)fmaxf(v.y * sc.y + sh.y, 0.f);
    o[2] = (_Float16)fmaxf(v.z * sc.z + sh.z, 0.f);
    o[3] = (_Float16)fmaxf(v.w * sc.w + sh.w, 0.f);
    *(f16x4*)(x + (size_t)i4 * 4) = o;
}

// ---------------- layer-4 GN+ReLU+maxpool (coalesced 2-stage) ----------------

__global__ __launch_bounds__(128) void pool4a(const float* __restrict__ y,
                                              const float* __restrict__ scale,
                                              const float* __restrict__ shift,
                                              float* __restrict__ partial) {
    int b = blockIdx.x >> 6;
    int pc = blockIdx.x & 63;          // 64 chunks of 64 points
    int o4 = threadIdx.x * 4;
    float4 sc = *(const float4*)(scale + b * 512 + o4);
    float4 sh = *(const float4*)(shift + b * 512 + o4);
    const float4* yb = (const float4*)(y + ((size_t)(b * NPTS) + pc * 64) * 512);
    float4 m = make_float4(-1e30f, -1e30f, -1e30f, -1e30f);
    #pragma unroll 4
    for (int p = 0; p < 64; p++) {
        float4 v = yb[(size_t)p * 128 + threadIdx.x];
        m.x = fmaxf(m.x, v.x * sc.x + sh.x);
        m.y = fmaxf(m.y, v.y * sc.y + sh.y);
        m.z = fmaxf(m.z, v.z * sc.z + sh.z);
        m.w = fmaxf(m.w, v.w * sc.w + sh.w);
    }
    *(float4*)(partial + (size_t)(b * 64 + pc) * 512 + o4) = m;
}

__global__ __launch_bounds__(512) void pool4b(const float* __restrict__ partial,
                                              float* __restrict__ g) {
    int b = blockIdx.x;
    int o = threadIdx.x;
    float m = -1e30f;
    for (int pc = 0; pc < 64; pc++)
        m = fmaxf(m, partial[(size_t)(b * 64 + pc) * 512 + o]);
    g[b * 512 + o] = fmaxf(m, 0.f);
}

// ---------------- FC head ----------------

__global__ __launch_bounds__(128) void head_kernel(const float* __restrict__ g,
                                                   const float* __restrict__ fc1w,
                                                   const float* __restrict__ fc1b,
                                                   const float* __restrict__ fc2w,
                                                   const float* __restrict__ fc2b,
                                                   float* __restrict__ out) {
    int b = blockIdx.x;
    int o = threadIdx.x;   // 128
    __shared__ float sg[512];
    for (int i = threadIdx.x; i < 512; i += 128) sg[i] = g[b * 512 + i];
    __syncthreads();
    float acc = fc1b[o];
    for (int c = 0; c < 512; c++) acc += sg[c] * fc1w[o * 512 + c];
    float h = fmaxf(acc, 0.f) * fc2w[o];
    for (int off = 32; off; off >>= 1) h += __shfl_down(h, off, 64);
    __shared__ float s2[2];
    if ((threadIdx.x & 63) == 0) s2[threadIdx.x >> 6] = h;
    __syncthreads();
    if (threadIdx.x == 0) out[b] = s2[0] + s2[1] + fc2b[0];
}

// ---------------- launch ----------------

extern "C" void kernel_launch(void* const* d_in, const int* in_sizes, int n_in,
                              void* d_out, int out_size, void* d_ws, size_t ws_size,
                              hipStream_t stream) {
    const float* vol  = (const float*)d_in[0];
    const float* w1   = (const float*)d_in[1];
    const float* gn1w = (const float*)d_in[2];
    const float* gn1b = (const float*)d_in[3];
    const float* w2   = (const float*)d_in[4];
    const float* gn2w = (const float*)d_in[5];
    const float* gn2b = (const float*)d_in[6];
    const float* w3   = (const float*)d_in[7];
    const float* gn3w = (const float*)d_in[8];
    const float* gn3b = (const float*)d_in[9];
    const float* w4   = (const float*)d_in[10];
    const float* gn4w = (const float*)d_in[11];
    const float* gn4b = (const float*)d_in[12];
    const float* fc1w = (const float*)d_in[13];
    const float* fc1b = (const float*)d_in[14];
    const float* fc2w = (const float*)d_in[15];
    const float* fc2b = (const float*)d_in[16];
    float* out = (float*)d_out;

    char* ws = (char*)d_ws;
    size_t cur = 0;
    auto alloc = [&](size_t bytes) -> void* {
        cur = (cur + 255) & ~(size_t)255;
        void* p = ws + cur;
        cur += bytes;
        return p;
    };
    int*      counts  = (int*)alloc((size_t)NB * NCHUNK * 4);
    int*      prefix  = (int*)alloc((size_t)NB * NCHUNK * 4);
    int*      totals  = (int*)alloc(64);
    float*    pts     = (float*)alloc((size_t)NB * 3 * NPTS * 4);
    float*    gbuf    = (float*)alloc((size_t)NB * 512 * 4);
    float*    pstat1  = (float*)alloc((size_t)NB * 8 * 16 * 2 * 4);
    float*    pstatG  = (float*)alloc((size_t)NB * 512 * 16 * 2 * 4);
    float*    scale   = (float*)alloc((size_t)NB * 512 * 4);
    float*    shift   = (float*)alloc((size_t)NB * 512 * 4);
    float*    partial = (float*)alloc((size_t)NB * 64 * 512 * 4);
    _Float16* w2h     = (_Float16*)alloc((size_t)128 * 64 * 2);
    _Float16* w3h     = (_Float16*)alloc((size_t)256 * 128 * 2);
    _Float16* w4h     = (_Float16*)alloc((size_t)512 * 256 * 2);
    _Float16* xbuf    = (_Float16*)alloc((size_t)NB * NPTS * 256 * 2);   // fp16 activations
    float*    ybuf    = (float*)alloc((size_t)NB * NPTS * 512 * 4);      // fp32 pre-norm

    // 1. points
    count_kernel<<<dim3(NB * NCHUNK), dim3(256), 0, stream>>>(vol, counts);
    scan_kernel<<<dim3(NB), dim3(1024), 0, stream>>>(counts, prefix, totals);
    points_kernel<<<dim3(NB * NPTS / 256), dim3(256), 0, stream>>>(vol, prefix, totals, pts);

    // 2. weight casts
    cast_w<<<dim3((128 * 64 + 255) / 256), dim3(256), 0, stream>>>(w2, w2h, 128 * 64);
    cast_w<<<dim3((256 * 128 + 255) / 256), dim3(256), 0, stream>>>(w3, w3h, 256 * 128);
    cast_w<<<dim3((512 * 256 + 255) / 256), dim3(256), 0, stream>>>(w4, w4h, 512 * 256);

    // 3. layer 1: 3 -> 64 (fused stats)
    conv1_kernel<<<dim3(NB * 16), dim3(256), 0, stream>>>(pts, w1, ybuf, pstat1);
    gn_finalize1<<<dim3(NB * 8), dim3(64), 0, stream>>>(pstat1, gn1w, gn1b, scale, shift);
    gn_norm_relu_t<64><<<dim3(NB * NPTS * 64 / 4 / 256), dim3(256), 0, stream>>>(ybuf, scale, shift, xbuf);

    // 4. layer 2: 64 -> 128 (fused stats)
    mfma_gemm<64, 128><<<dim3(16, 2, NB), dim3(256), 0, stream>>>(xbuf, w2h, ybuf, pstatG);
    gn_finalizeG<128><<<dim3(NB * 8), dim3(256), 0, stream>>>(pstatG, gn2w, gn2b, scale, shift);
    gn_norm_relu_t<128><<<dim3(NB * NPTS * 128 / 4 / 256), dim3(256), 0, stream>>>(ybuf, scale, shift, xbuf);

    // 5. layer 3: 128 -> 256 (fused stats)
    mfma_gemm<128, 256><<<dim3(16, 4, NB), dim3(256), 0, stream>>>(xbuf, w3h, ybuf, pstatG);
    gn_finalizeG<256><<<dim3(NB * 8), dim3(256), 0, stream>>>(pstatG, gn3w, gn3b, scale, shift);
    gn_norm_relu_t<256><<<dim3(NB * NPTS * 256 / 4 / 256), dim3(256), 0, stream>>>(ybuf, scale, shift, xbuf);

    // 6. layer 4: 256 -> 512 (fused stats), then finalize + fused norm/relu/maxpool
    mfma_gemm<256, 512><<<dim3(16, 8, NB), dim3(256), 0, stream>>>(xbuf, w4h, ybuf, pstatG);
    gn_finalizeG<512><<<dim3(NB * 8), dim3(256), 0, stream>>>(pstatG, gn4w, gn4b, scale, shift);
    pool4a<<<dim3(NB * 64), dim3(128), 0, stream>>>(ybuf, scale, shift, partial);
    pool4b<<<dim3(NB), dim3(512), 0, stream>>>(partial, gbuf);

    // 7. head
    head_kernel<<<dim3(NB), dim3(128), 0, stream>>>(gbuf, fc1w, fc1b, fc2w, fc2b, out);
}

// Round 4
// 198.189 us; speedup vs baseline: 3.9337x; 1.4961x over previous
//
#include <hip/hip_runtime.h>
#include <hip/hip_bf16.h>

#define NB 16
#define VOX 884736        // 96*96*96
#define NPTS 4096
#define CHUNK 1024
#define NCHUNK 864        // VOX / CHUNK

typedef _Float16 f16x8 __attribute__((ext_vector_type(8)));
typedef _Float16 f16x4 __attribute__((ext_vector_type(4)));
typedef float f32x4 __attribute__((ext_vector_type(4)));

// ---------------- point extraction (unchanged, verified) ----------------

__global__ __launch_bounds__(256) void count_kernel(const float* __restrict__ vol,
                                                    int* __restrict__ counts) {
    int blk = blockIdx.x;  // b*NCHUNK + c
    const float4* v4 = (const float4*)(vol + (size_t)blk * CHUNK);
    float4 v = v4[threadIdx.x];
    int cnt = (v.x > 0.5f) + (v.y > 0.5f) + (v.z > 0.5f) + (v.w > 0.5f);
    for (int off = 32; off; off >>= 1) cnt += __shfl_down(cnt, off, 64);
    __shared__ int s[4];
    if ((threadIdx.x & 63) == 0) s[threadIdx.x >> 6] = cnt;
    __syncthreads();
    if (threadIdx.x == 0) counts[blk] = s[0] + s[1] + s[2] + s[3];
}

__global__ __launch_bounds__(1024) void scan_kernel(const int* __restrict__ counts,
                                                    int* __restrict__ prefix,
                                                    int* __restrict__ totals) {
    __shared__ int s[1024];
    int b = blockIdx.x, t = threadIdx.x;
    int v = (t < NCHUNK) ? counts[b * NCHUNK + t] : 0;
    s[t] = v;
    __syncthreads();
    for (int off = 1; off < 1024; off <<= 1) {
        int x = (t >= off) ? s[t - off] : 0;
        __syncthreads();
        s[t] += x;
        __syncthreads();
    }
    if (t < NCHUNK) prefix[b * NCHUNK + t] = s[t] - v;   // exclusive
    if (t == NCHUNK - 1) totals[b] = s[t];
}

__global__ __launch_bounds__(256) void points_kernel(const float* __restrict__ vol,
                                                     const int* __restrict__ prefix,
                                                     const int* __restrict__ totals,
                                                     float* __restrict__ pts) {
    int gid = blockIdx.x * 256 + threadIdx.x;  // 0 .. NB*NPTS
    int b = gid >> 12;
    int p = gid & (NPTS - 1);
    int n = totals[b];
    float px = 0.f, py = 0.f, pz = 0.f;
    if (n > 0) {
        int k;
        if (n >= NPTS) {
            float t = (float)p * ((float)n - 1.0f);
            t = t / 4095.0f;
            k = (int)t;
            if (k > n - 1) k = n - 1;
            if (k < 0) k = 0;
        } else {
            k = p % n;
        }
        const int* pref = prefix + b * NCHUNK;
        int lo = 0, hi = NCHUNK - 1;
        while (lo < hi) {
            int mid = (lo + hi + 1) >> 1;
            if (pref[mid] <= k) lo = mid; else hi = mid - 1;
        }
        int r = k - pref[lo];
        const float4* v4 = (const float4*)(vol + (size_t)b * VOX + (size_t)lo * CHUNK);
        int flat = 0, acc = 0;
        for (int i = 0; i < CHUNK / 4; i++) {
            float4 q = v4[i];
            int c0 = q.x > 0.5f, c1 = q.y > 0.5f, c2 = q.z > 0.5f, c3 = q.w > 0.5f;
            int s4 = c0 + c1 + c2 + c3;
            if (acc + s4 > r) {
                int rr = r - acc;
                int j;
                if (c0 && rr == 0) j = 0;
                else {
                    rr -= c0;
                    if (c1 && rr == 0) j = 1;
                    else {
                        rr -= c1;
                        if (c2 && rr == 0) j = 2; else j = 3;
                    }
                }
                flat = lo * CHUNK + i * 4 + j;
                break;
            }
            acc += s4;
        }
        int dd = flat / 9216;           // 96*96
        int rem = flat - dd * 9216;
        int hh = rem / 96;
        int ww = rem - hh * 96;
        px = (float)dd / 95.0f * 2.0f - 1.0f;
        py = (float)hh / 95.0f * 2.0f - 1.0f;
        pz = (float)ww / 95.0f * 2.0f - 1.0f;
    }
    pts[((size_t)b * 3 + 0) * NPTS + p] = px;
    pts[((size_t)b * 3 + 1) * NPTS + p] = py;
    pts[((size_t)b * 3 + 2) * NPTS + p] = pz;
}

// ---------------- weight cast fp32 -> fp16 fragment layout ----------------
// Wfrag[ob][cb][lane][e] : o = ob*16+(lane&15), c = cb*32+(lane>>4)*8+e

template <int CIN, int COUT>
__global__ __launch_bounds__(256) void cast_w_frag(const float* __restrict__ wf,
                                                   _Float16* __restrict__ wh) {
    constexpr int NCB = CIN / 32;
    constexpr int NCHK = (COUT / 16) * NCB * 64;
    int t = blockIdx.x * 256 + threadIdx.x;
    if (t >= NCHK) return;
    int lane = t & 63;
    int cb = (t >> 6) % NCB;
    int ob = t / (64 * NCB);
    int o = ob * 16 + (lane & 15);
    int c0 = cb * 32 + (lane >> 4) * 8;
    const float* src = wf + (size_t)o * CIN + c0;
    f16x8 v;
    #pragma unroll
    for (int e = 0; e < 8; e++) v[e] = (_Float16)src[e];
    *(f16x8*)(wh + (size_t)t * 8) = v;
}

// ---------------- layer 1 (3 -> 64): raw y1 in A-layout fp16, fused pstat ----------------
// A-layout: X[p16][cb][lane][e] : p = p16*16+(lane&15), c = cb*32+(lane>>4)*8+e

__global__ __launch_bounds__(256) void conv1_kernel(const float* __restrict__ pts,
                                                    const float* __restrict__ w1,
                                                    _Float16* __restrict__ y,
                                                    float* __restrict__ pstat1) {
    int b = blockIdx.x >> 4;
    int pc = blockIdx.x & 15;
    int p = pc * 256 + threadIdx.x;
    float x0 = pts[((size_t)b * 3 + 0) * NPTS + p];
    float x1 = pts[((size_t)b * 3 + 1) * NPTS + p];
    float x2 = pts[((size_t)b * 3 + 2) * NPTS + p];
    float yv[64];
    float s[8] = {}, q[8] = {};
    #pragma unroll
    for (int o = 0; o < 64; o++) {
        float a = w1[o * 3 + 0] * x0 + w1[o * 3 + 1] * x1 + w1[o * 3 + 2] * x2;
        yv[o] = a;
        s[o >> 3] += a;
        q[o >> 3] += a * a;
    }
    int p16g = (b * NPTS + p) >> 4;
    int pr = p & 15;
    #pragma unroll
    for (int cb = 0; cb < 2; cb++)
        #pragma unroll
        for (int k = 0; k < 4; k++) {
            f16x8 v;
            #pragma unroll
            for (int e = 0; e < 8; e++) v[e] = (_Float16)yv[cb * 32 + k * 8 + e];
            *(f16x8*)(y + (((size_t)p16g * 2 + cb) * 64 + k * 16 + pr) * 8) = v;
        }
    __shared__ float red[4][8][2];
    int wv = threadIdx.x >> 6;
    #pragma unroll
    for (int g = 0; g < 8; g++) {
        float S = s[g], Q = q[g];
        for (int off = 32; off; off >>= 1) {
            S += __shfl_down(S, off, 64);
            Q += __shfl_down(Q, off, 64);
        }
        if ((threadIdx.x & 63) == 0) { red[wv][g][0] = S; red[wv][g][1] = Q; }
    }
    __syncthreads();
    if (threadIdx.x < 8) {
        int g = threadIdx.x;
        float S = red[0][g][0] + red[1][g][0] + red[2][g][0] + red[3][g][0];
        float Q = red[0][g][1] + red[1][g][1] + red[2][g][1] + red[3][g][1];
        float* d = pstat1 + (((size_t)(b * 8 + g)) * 16 + pc) * 2;
        d[0] = S; d[1] = Q;
    }
}

__global__ __launch_bounds__(64) void gn_finalize1(const float* __restrict__ pstat,
                                                   const float* __restrict__ gamma,
                                                   const float* __restrict__ beta,
                                                   float* __restrict__ scale,
                                                   float* __restrict__ shift) {
    int b = blockIdx.x >> 3, g = blockIdx.x & 7;
    const float* base = pstat + (size_t)(b * 8 + g) * 32;
    float S = 0.f, Q = 0.f;
    if (threadIdx.x < 16) { S = base[threadIdx.x * 2]; Q = base[threadIdx.x * 2 + 1]; }
    for (int off = 8; off; off >>= 1) {
        S += __shfl_down(S, off, 64);
        Q += __shfl_down(Q, off, 64);
    }
    __shared__ float ms[2];
    if (threadIdx.x == 0) {
        float inv = 1.0f / (8.0f * 4096.0f);
        float mu = S * inv;
        float var = Q * inv - mu * mu;
        if (var < 0.f) var = 0.f;
        ms[0] = mu; ms[1] = rsqrtf(var + 1e-5f);
    }
    __syncthreads();
    if (threadIdx.x < 8) {
        int c = g * 8 + threadIdx.x;
        float ga = gamma[c] * ms[1];
        scale[b * 64 + c] = ga;
        shift[b * 64 + c] = beta[c] - ms[0] * ga;
    }
}

// ---------------- norm1: elementwise on A64 layout (no transpose needed) ----------------

__global__ __launch_bounds__(256) void norm1(const _Float16* __restrict__ y,
                                             const float* __restrict__ scale,
                                             const float* __restrict__ shift,
                                             _Float16* __restrict__ x) {
    int t = blockIdx.x * 256 + threadIdx.x;     // f16x8 chunk id
    int lane = t & 63;
    int cb = (t >> 6) & 1;
    int p16g = t >> 7;
    int b = p16g >> 8;                          // 256 p16 per batch
    int c0 = cb * 32 + (lane >> 4) * 8;
    f16x8 v = *(const f16x8*)(y + (size_t)t * 8);
    float4 sc0 = *(const float4*)(scale + b * 64 + c0);
    float4 sc1 = *(const float4*)(scale + b * 64 + c0 + 4);
    float4 sh0 = *(const float4*)(shift + b * 64 + c0);
    float4 sh1 = *(const float4*)(shift + b * 64 + c0 + 4);
    f16x8 o;
    o[0] = (_Float16)fmaxf((float)v[0] * sc0.x + sh0.x, 0.f);
    o[1] = (_Float16)fmaxf((float)v[1] * sc0.y + sh0.y, 0.f);
    o[2] = (_Float16)fmaxf((float)v[2] * sc0.z + sh0.z, 0.f);
    o[3] = (_Float16)fmaxf((float)v[3] * sc0.w + sh0.w, 0.f);
    o[4] = (_Float16)fmaxf((float)v[4] * sc1.x + sh1.x, 0.f);
    o[5] = (_Float16)fmaxf((float)v[5] * sc1.y + sh1.y, 0.f);
    o[6] = (_Float16)fmaxf((float)v[6] * sc1.z + sh1.z, 0.f);
    o[7] = (_Float16)fmaxf((float)v[7] * sc1.w + sh1.w, 0.f);
    *(f16x8*)(x + (size_t)t * 8) = o;
}

// ---------------- MFMA GEMM, fragment-native I/O, fused pstat ----------------
// D-native y layout per (Pblk,Oblk) 64x64 tile: [of][pf][lane][j]
//   p = Pblk*64 + pf*16 + (lane>>4)*4 + j ; o = Oblk*64 + of*16 + (lane&15)

template <int CIN, int COUT>
__global__ __launch_bounds__(256) void mfma_gemm(const _Float16* __restrict__ xa,
                                                 const _Float16* __restrict__ wf,
                                                 _Float16* __restrict__ y,
                                                 float* __restrict__ pstat) {
    constexpr int NCB = CIN / 32;
    int b = blockIdx.z;
    int wv = threadIdx.x >> 6;
    int lane = threadIdx.x & 63;
    int lr = lane & 15;
    int lk = lane >> 4;
    int P16 = (b * NPTS + blockIdx.x * 256 + wv * 64) >> 4;
    int O16 = blockIdx.y * 4;
    f32x4 acc[4][4] = {};
    #pragma unroll 2
    for (int cb = 0; cb < NCB; cb++) {
        f16x8 af[4], bf[4];
        #pragma unroll
        for (int i = 0; i < 4; i++)
            af[i] = *(const f16x8*)(xa + (((size_t)(P16 + i) * NCB + cb) * 64 + lane) * 8);
        #pragma unroll
        for (int i = 0; i < 4; i++)
            bf[i] = *(const f16x8*)(wf + (((size_t)(O16 + i) * NCB + cb) * 64 + lane) * 8);
        #pragma unroll
        for (int pf = 0; pf < 4; pf++)
            #pragma unroll
            for (int of = 0; of < 4; of++)
                acc[pf][of] = __builtin_amdgcn_mfma_f32_16x16x32_f16(af[pf], bf[of], acc[pf][of], 0, 0, 0);
    }
    // D-native fp16 store: fully coalesced 8B/lane
    int Pblk = (b * NPTS + blockIdx.x * 256 + wv * 64) >> 6;
    _Float16* yt = y + ((size_t)Pblk * (COUT / 64) + blockIdx.y) * 4096;
    #pragma unroll
    for (int of = 0; of < 4; of++)
        #pragma unroll
        for (int pf = 0; pf < 4; pf++) {
            f16x4 v;
            #pragma unroll
            for (int j = 0; j < 4; j++) v[j] = (_Float16)acc[pf][of][j];
            *(f16x4*)(yt + ((size_t)(of * 4 + pf) * 64 + lane) * 4) = v;
        }
    // fused partial stats (from exact f32 accumulators)
    __shared__ float sred[4][64][2];
    #pragma unroll
    for (int of = 0; of < 4; of++) {
        float S = 0.f, Q = 0.f;
        #pragma unroll
        for (int pf = 0; pf < 4; pf++)
            #pragma unroll
            for (int j = 0; j < 4; j++) {
                float v = acc[pf][of][j];
                S += v; Q += v * v;
            }
        S += __shfl_xor(S, 16, 64); Q += __shfl_xor(Q, 16, 64);
        S += __shfl_xor(S, 32, 64); Q += __shfl_xor(Q, 32, 64);
        if (lk == 0) { sred[wv][of * 16 + lr][0] = S; sred[wv][of * 16 + lr][1] = Q; }
    }
    __syncthreads();
    if (threadIdx.x < 64) {
        int o = threadIdx.x;
        float S = sred[0][o][0] + sred[1][o][0] + sred[2][o][0] + sred[3][o][0];
        float Q = sred[0][o][1] + sred[1][o][1] + sred[2][o][1] + sred[3][o][1];
        float* d = pstat + (((size_t)b * COUT + blockIdx.y * 64 + o) * 16 + blockIdx.x) * 2;
        d[0] = S; d[1] = Q;
    }
}

// ---------------- GN finalize (layers 2,3) ----------------

template <int C>
__global__ __launch_bounds__(256) void gn_finalizeG(const float* __restrict__ pstat,
                                                    const float* __restrict__ gamma,
                                                    const float* __restrict__ beta,
                                                    float* __restrict__ scale,
                                                    float* __restrict__ shift) {
    constexpr int GS = C / 8;
    int b = blockIdx.x >> 3, g = blockIdx.x & 7;
    const float* base = pstat + ((size_t)b * C + g * GS) * 32;
    float S = 0.f, Q = 0.f;
    for (int i = threadIdx.x; i < GS * 16; i += 256) { S += base[2 * i]; Q += base[2 * i + 1]; }
    for (int off = 32; off; off >>= 1) {
        S += __shfl_down(S, off, 64);
        Q += __shfl_down(Q, off, 64);
    }
    __shared__ float ss[8];
    if ((threadIdx.x & 63) == 0) {
        ss[(threadIdx.x >> 6) * 2] = S;
        ss[(threadIdx.x >> 6) * 2 + 1] = Q;
    }
    __syncthreads();
    __shared__ float ms[2];
    if (threadIdx.x == 0) {
        float St = ss[0] + ss[2] + ss[4] + ss[6];
        float Qt = ss[1] + ss[3] + ss[5] + ss[7];
        float inv = 1.0f / ((float)GS * 4096.0f);
        float mu = St * inv;
        float var = Qt * inv - mu * mu;
        if (var < 0.f) var = 0.f;
        ms[0] = mu; ms[1] = rsqrtf(var + 1e-5f);
    }
    __syncthreads();
    for (int i = threadIdx.x; i < GS; i += 256) {
        int c = g * GS + i;
        float ga = gamma[c] * ms[1];
        scale[(size_t)b * C + c] = ga;
        shift[(size_t)b * C + c] = beta[c] - ms[0] * ga;
    }
}

// ---------------- normG: D-native y -> norm+ReLU -> A-layout x (LDS transpose) ----------------

template <int C>
__global__ __launch_bounds__(256) void normG(const _Float16* __restrict__ y,
                                             const float* __restrict__ scale,
                                             const float* __restrict__ shift,
                                             _Float16* __restrict__ x) {
    __shared__ _Float16 sl[64 * C];
    int Pblk = blockIdx.x;
    int b = Pblk >> 6;
    const _Float16* yt = y + (size_t)Pblk * 64 * C;
    constexpr int NCH = 64 * C / 4;      // f16x4 chunks per tile
    for (int q = threadIdx.x; q < NCH; q += 256) {
        int lane = q & 63;
        int pf = (q >> 6) & 3;
        int of = (q >> 8) & 3;
        int Ob = q >> 10;
        int o = Ob * 64 + of * 16 + (lane & 15);
        int pbase = pf * 16 + (lane >> 4) * 4;
        f16x4 v = *(const f16x4*)(yt + (size_t)q * 4);
        float sc = scale[(size_t)b * C + o];
        float sh = shift[(size_t)b * C + o];
        int ch = o >> 3;
        #pragma unroll
        for (int e = 0; e < 4; e++) {
            int p = pbase + e;
            float r = fmaxf((float)v[e] * sc + sh, 0.f);
            sl[p * C + ((ch ^ (p & 7)) << 3) + (o & 7)] = (_Float16)r;
        }
    }
    __syncthreads();
    int wv = threadIdx.x >> 6;
    int lane = threadIdx.x & 63;
    int p = wv * 16 + (lane & 15);
    int k = lane >> 4;
    int P16 = Pblk * 4 + wv;
    #pragma unroll
    for (int cb = 0; cb < C / 32; cb++) {
        int ch = cb * 4 + k;
        f16x8 v = *(const f16x8*)(sl + p * C + ((ch ^ (p & 7)) << 3));
        *(f16x8*)(x + (((size_t)P16 * (C / 32) + cb) * 64 + lane) * 8) = v;
    }
}

// ---------------- layer 4: GEMM with pooled epilogue (no y materialization) ----------------
// pstat4[b][o][pb][4] = (sum, sumsq, max, min) over that p-block's 256 points

__global__ __launch_bounds__(256) void mfma_gemm_pool(const _Float16* __restrict__ xa,
                                                      const _Float16* __restrict__ wf,
                                                      float* __restrict__ pstat4) {
    constexpr int CIN = 256, NCB = CIN / 32;
    int b = blockIdx.z;
    int wv = threadIdx.x >> 6;
    int lane = threadIdx.x & 63;
    int lr = lane & 15;
    int lk = lane >> 4;
    int P16 = (b * NPTS + blockIdx.x * 256 + wv * 64) >> 4;
    int O16 = blockIdx.y * 4;
    f32x4 acc[4][4] = {};
    #pragma unroll 2
    for (int cb = 0; cb < NCB; cb++) {
        f16x8 af[4], bf[4];
        #pragma unroll
        for (int i = 0; i < 4; i++)
            af[i] = *(const f16x8*)(xa + (((size_t)(P16 + i) * NCB + cb) * 64 + lane) * 8);
        #pragma unroll
        for (int i = 0; i < 4; i++)
            bf[i] = *(const f16x8*)(wf + (((size_t)(O16 + i) * NCB + cb) * 64 + lane) * 8);
        #pragma unroll
        for (int pf = 0; pf < 4; pf++)
            #pragma unroll
            for (int of = 0; of < 4; of++)
                acc[pf][of] = __builtin_amdgcn_mfma_f32_16x16x32_f16(af[pf], bf[of], acc[pf][of], 0, 0, 0);
    }
    __shared__ float sred[4][64][4];
    #pragma unroll
    for (int of = 0; of < 4; of++) {
        float S = 0.f, Q = 0.f, MX = -1e30f, MN = 1e30f;
        #pragma unroll
        for (int pf = 0; pf < 4; pf++)
            #pragma unroll
            for (int j = 0; j < 4; j++) {
                float v = acc[pf][of][j];
                S += v; Q += v * v;
                MX = fmaxf(MX, v); MN = fminf(MN, v);
            }
        S += __shfl_xor(S, 16, 64); Q += __shfl_xor(Q, 16, 64);
        MX = fmaxf(MX, __shfl_xor(MX, 16, 64)); MN = fminf(MN, __shfl_xor(MN, 16, 64));
        S += __shfl_xor(S, 32, 64); Q += __shfl_xor(Q, 32, 64);
        MX = fmaxf(MX, __shfl_xor(MX, 32, 64)); MN = fminf(MN, __shfl_xor(MN, 32, 64));
        if (lk == 0) {
            sred[wv][of * 16 + lr][0] = S;
            sred[wv][of * 16 + lr][1] = Q;
            sred[wv][of * 16 + lr][2] = MX;
            sred[wv][of * 16 + lr][3] = MN;
        }
    }
    __syncthreads();
    if (threadIdx.x < 64) {
        int o = threadIdx.x;
        float S = sred[0][o][0] + sred[1][o][0] + sred[2][o][0] + sred[3][o][0];
        float Q = sred[0][o][1] + sred[1][o][1] + sred[2][o][1] + sred[3][o][1];
        float MX = fmaxf(fmaxf(sred[0][o][2], sred[1][o][2]), fmaxf(sred[2][o][2], sred[3][o][2]));
        float MN = fminf(fminf(sred[0][o][3], sred[1][o][3]), fminf(sred[2][o][3], sred[3][o][3]));
        *(float4*)(pstat4 + (((size_t)b * 512 + blockIdx.y * 64 + o) * 16 + blockIdx.x) * 4) =
            make_float4(S, Q, MX, MN);
    }
}

// ---------------- pool finalize: stats + affine-max + relu -> g[b][512] ----------------

__global__ __launch_bounds__(256) void pool_final(const float* __restrict__ pstat4,
                                                  const float* __restrict__ gamma,
                                                  const float* __restrict__ beta,
                                                  float* __restrict__ g) {
    int b = blockIdx.x;
    __shared__ float sS[512], sQ[512];
    __shared__ float ms[8][2];
    float Sa[2], Qa[2], MXa[2], MNa[2];
    #pragma unroll
    for (int h = 0; h < 2; h++) {
        int o = threadIdx.x + h * 256;
        float S = 0.f, Q = 0.f, MX = -1e30f, MN = 1e30f;
        for (int pb = 0; pb < 16; pb++) {
            float4 v = *(const float4*)(pstat4 + (((size_t)b * 512 + o) * 16 + pb) * 4);
            S += v.x; Q += v.y; MX = fmaxf(MX, v.z); MN = fminf(MN, v.w);
        }
        Sa[h] = S; Qa[h] = Q; MXa[h] = MX; MNa[h] = MN;
        sS[o] = S; sQ[o] = Q;
    }
    __syncthreads();
    if (threadIdx.x < 8) {
        int gr = threadIdx.x;
        float St = 0.f, Qt = 0.f;
        for (int i = 0; i < 64; i++) { St += sS[gr * 64 + i]; Qt += sQ[gr * 64 + i]; }
        float inv = 1.0f / (64.0f * 4096.0f);
        float mu = St * inv;
        float var = Qt * inv - mu * mu;
        if (var < 0.f) var = 0.f;
        ms[gr][0] = mu; ms[gr][1] = rsqrtf(var + 1e-5f);
    }
    __syncthreads();
    #pragma unroll
    for (int h = 0; h < 2; h++) {
        int o = threadIdx.x + h * 256;
        int gr = o >> 6;
        float sc = gamma[o] * ms[gr][1];
        float sh = beta[o] - ms[gr][0] * sc;
        float m = (sc >= 0.f ? MXa[h] : MNa[h]) * sc + sh;
        g[b * 512 + o] = fmaxf(m, 0.f);
    }
}

// ---------------- FC head ----------------

__global__ __launch_bounds__(128) void head_kernel(const float* __restrict__ g,
                                                   const float* __restrict__ fc1w,
                                                   const float* __restrict__ fc1b,
                                                   const float* __restrict__ fc2w,
                                                   const float* __restrict__ fc2b,
                                                   float* __restrict__ out) {
    int b = blockIdx.x;
    int o = threadIdx.x;   // 128
    __shared__ float sg[512];
    for (int i = threadIdx.x; i < 512; i += 128) sg[i] = g[b * 512 + i];
    __syncthreads();
    float acc = fc1b[o];
    for (int c = 0; c < 512; c++) acc += sg[c] * fc1w[o * 512 + c];
    float h = fmaxf(acc, 0.f) * fc2w[o];
    for (int off = 32; off; off >>= 1) h += __shfl_down(h, off, 64);
    __shared__ float s2[2];
    if ((threadIdx.x & 63) == 0) s2[threadIdx.x >> 6] = h;
    __syncthreads();
    if (threadIdx.x == 0) out[b] = s2[0] + s2[1] + fc2b[0];
}

// ---------------- launch ----------------

extern "C" void kernel_launch(void* const* d_in, const int* in_sizes, int n_in,
                              void* d_out, int out_size, void* d_ws, size_t ws_size,
                              hipStream_t stream) {
    const float* vol  = (const float*)d_in[0];
    const float* w1   = (const float*)d_in[1];
    const float* gn1w = (const float*)d_in[2];
    const float* gn1b = (const float*)d_in[3];
    const float* w2   = (const float*)d_in[4];
    const float* gn2w = (const float*)d_in[5];
    const float* gn2b = (const float*)d_in[6];
    const float* w3   = (const float*)d_in[7];
    const float* gn3w = (const float*)d_in[8];
    const float* gn3b = (const float*)d_in[9];
    const float* w4   = (const float*)d_in[10];
    const float* gn4w = (const float*)d_in[11];
    const float* gn4b = (const float*)d_in[12];
    const float* fc1w = (const float*)d_in[13];
    const float* fc1b = (const float*)d_in[14];
    const float* fc2w = (const float*)d_in[15];
    const float* fc2b = (const float*)d_in[16];
    float* out = (float*)d_out;

    char* ws = (char*)d_ws;
    size_t cur = 0;
    auto alloc = [&](size_t bytes) -> void* {
        cur = (cur + 255) & ~(size_t)255;
        void* p = ws + cur;
        cur += bytes;
        return p;
    };
    int*      counts  = (int*)alloc((size_t)NB * NCHUNK * 4);
    int*      prefix  = (int*)alloc((size_t)NB * NCHUNK * 4);
    int*      totals  = (int*)alloc(64);
    float*    pts     = (float*)alloc((size_t)NB * 3 * NPTS * 4);
    float*    gbuf    = (float*)alloc((size_t)NB * 512 * 4);
    float*    pstat1  = (float*)alloc((size_t)NB * 8 * 16 * 2 * 4);
    float*    pstatG  = (float*)alloc((size_t)NB * 512 * 16 * 2 * 4);
    float*    pstat4  = (float*)alloc((size_t)NB * 512 * 16 * 4 * 4);
    float*    scale   = (float*)alloc((size_t)NB * 512 * 4);
    float*    shift   = (float*)alloc((size_t)NB * 512 * 4);
    _Float16* w2f     = (_Float16*)alloc((size_t)128 * 64 * 2);
    _Float16* w3f     = (_Float16*)alloc((size_t)256 * 128 * 2);
    _Float16* w4f     = (_Float16*)alloc((size_t)512 * 256 * 2);
    _Float16* y1      = (_Float16*)alloc((size_t)NB * NPTS * 64 * 2);
    _Float16* x1      = (_Float16*)alloc((size_t)NB * NPTS * 64 * 2);
    _Float16* y2      = (_Float16*)alloc((size_t)NB * NPTS * 128 * 2);
    _Float16* x2      = (_Float16*)alloc((size_t)NB * NPTS * 128 * 2);
    _Float16* y3      = (_Float16*)alloc((size_t)NB * NPTS * 256 * 2);
    _Float16* x3      = (_Float16*)alloc((size_t)NB * NPTS * 256 * 2);

    // 1. points
    count_kernel<<<dim3(NB * NCHUNK), dim3(256), 0, stream>>>(vol, counts);
    scan_kernel<<<dim3(NB), dim3(1024), 0, stream>>>(counts, prefix, totals);
    points_kernel<<<dim3(NB * NPTS / 256), dim3(256), 0, stream>>>(vol, prefix, totals, pts);

    // 2. weight casts to fragment layout
    cast_w_frag<64, 128><<<dim3(4), dim3(256), 0, stream>>>(w2, w2f);
    cast_w_frag<128, 256><<<dim3(16), dim3(256), 0, stream>>>(w3, w3f);
    cast_w_frag<256, 512><<<dim3(64), dim3(256), 0, stream>>>(w4, w4f);

    // 3. layer 1: 3 -> 64 (A-layout raw + fused stats)
    conv1_kernel<<<dim3(NB * 16), dim3(256), 0, stream>>>(pts, w1, y1, pstat1);
    gn_finalize1<<<dim3(NB * 8), dim3(64), 0, stream>>>(pstat1, gn1w, gn1b, scale, shift);
    norm1<<<dim3(NB * NPTS * 64 / 8 / 256), dim3(256), 0, stream>>>(y1, scale, shift, x1);

    // 4. layer 2: 64 -> 128
    mfma_gemm<64, 128><<<dim3(16, 2, NB), dim3(256), 0, stream>>>(x1, w2f, y2, pstatG);
    gn_finalizeG<128><<<dim3(NB * 8), dim3(256), 0, stream>>>(pstatG, gn2w, gn2b, scale, shift);
    normG<128><<<dim3(NB * 64), dim3(256), 0, stream>>>(y2, scale, shift, x2);

    // 5. layer 3: 128 -> 256
    mfma_gemm<128, 256><<<dim3(16, 4, NB), dim3(256), 0, stream>>>(x2, w3f, y3, pstatG);
    gn_finalizeG<256><<<dim3(NB * 8), dim3(256), 0, stream>>>(pstatG, gn3w, gn3b, scale, shift);
    normG<256><<<dim3(NB * 64), dim3(256), 0, stream>>>(y3, scale, shift, x3);

    // 6. layer 4: 256 -> 512 with pooled epilogue (no y4), then finalize
    mfma_gemm_pool<<<dim3(16, 8, NB), dim3(256), 0, stream>>>(x3, w4f, pstat4);
    pool_final<<<dim3(NB), dim3(256), 0, stream>>>(pstat4, gn4w, gn4b, gbuf);

    // 7. head
    head_kernel<<<dim3(NB), dim3(128), 0, stream>>>(gbuf, fc1w, fc1b, fc2w, fc2b, out);
}

// Round 5
// 139.369 us; speedup vs baseline: 5.5940x; 1.4220x over previous
//
#include <hip/hip_runtime.h>
#include <hip/hip_bf16.h>

#define NB 16
#define VOX 884736        // 96*96*96
#define NPTS 4096
#define CHUNK 1024
#define NCHUNK 864        // VOX / CHUNK

typedef _Float16 f16x8 __attribute__((ext_vector_type(8)));
typedef _Float16 f16x4 __attribute__((ext_vector_type(4)));
typedef float f32x4 __attribute__((ext_vector_type(4)));

// ---------------- count + bitmask ----------------
// bits[blk][w] : bit j = (vol[blk*1024 + w*64 + j] > 0.5)

__global__ __launch_bounds__(256) void count_kernel(const float* __restrict__ vol,
                                                    int* __restrict__ counts,
                                                    unsigned long long* __restrict__ bits) {
    int blk = blockIdx.x;  // b*NCHUNK + c
    const float4* v4 = (const float4*)(vol + (size_t)blk * CHUNK);
    float4 v = v4[threadIdx.x];
    int nib = (v.x > 0.5f) | ((v.y > 0.5f) << 1) | ((v.z > 0.5f) << 2) | ((v.w > 0.5f) << 3);
    __shared__ unsigned char nibs[256];
    nibs[threadIdx.x] = (unsigned char)nib;
    int cnt = __popc(nib);
    for (int off = 32; off; off >>= 1) cnt += __shfl_down(cnt, off, 64);
    __shared__ int s[4];
    if ((threadIdx.x & 63) == 0) s[threadIdx.x >> 6] = cnt;
    __syncthreads();
    if (threadIdx.x < 16) {
        unsigned long long wd = 0;
        #pragma unroll
        for (int i = 0; i < 16; i++)
            wd |= (unsigned long long)nibs[threadIdx.x * 16 + i] << (4 * i);
        bits[(size_t)blk * 16 + threadIdx.x] = wd;
    }
    if (threadIdx.x == 0) counts[blk] = s[0] + s[1] + s[2] + s[3];
}

__global__ __launch_bounds__(1024) void scan_kernel(const int* __restrict__ counts,
                                                    int* __restrict__ prefix,
                                                    int* __restrict__ totals) {
    __shared__ int s[1024];
    int b = blockIdx.x, t = threadIdx.x;
    int v = (t < NCHUNK) ? counts[b * NCHUNK + t] : 0;
    s[t] = v;
    __syncthreads();
    for (int off = 1; off < 1024; off <<= 1) {
        int x = (t >= off) ? s[t - off] : 0;
        __syncthreads();
        s[t] += x;
        __syncthreads();
    }
    if (t < NCHUNK) prefix[b * NCHUNK + t] = s[t] - v;   // exclusive
    if (t == NCHUNK - 1) totals[b] = s[t];
}

// ---------------- points via bitmask rank-select, fused conv1 stats ----------------

__global__ __launch_bounds__(256) void points_kernel(const unsigned long long* __restrict__ bits,
                                                     const int* __restrict__ prefix,
                                                     const int* __restrict__ totals,
                                                     const float* __restrict__ w1,
                                                     float* __restrict__ pts,
                                                     float* __restrict__ pstat1) {
    int b = blockIdx.x >> 4;
    int pc = blockIdx.x & 15;
    int p = pc * 256 + threadIdx.x;
    __shared__ int spref[NCHUNK];
    __shared__ float sw1[192];
    for (int i = threadIdx.x; i < NCHUNK; i += 256) spref[i] = prefix[b * NCHUNK + i];
    if (threadIdx.x < 192) sw1[threadIdx.x] = w1[threadIdx.x];
    __syncthreads();
    int n = totals[b];
    float px = 0.f, py = 0.f, pz = 0.f;
    if (n > 0) {
        int k;
        if (n >= NPTS) {
            float t = (float)p * ((float)n - 1.0f);
            t = t / 4095.0f;
            k = (int)t;
            if (k > n - 1) k = n - 1;
            if (k < 0) k = 0;
        } else {
            k = p % n;
        }
        int lo = 0, hi = NCHUNK - 1;
        while (lo < hi) {
            int mid = (lo + hi + 1) >> 1;
            if (spref[mid] <= k) lo = mid; else hi = mid - 1;
        }
        int rr = k - spref[lo];
        const unsigned long long* wb = bits + ((size_t)b * NCHUNK + lo) * 16;
        unsigned long long chosen = 0;
        int wordidx = 0;
        bool found = false;
        #pragma unroll
        for (int w = 0; w < 16; w++) {
            unsigned long long m = wb[w];
            int pcnt = __popcll(m);
            bool take = (!found) && (rr < pcnt);
            if (take) { chosen = m; wordidx = w; found = true; }
            if (!found) rr -= pcnt;
        }
        // rr-th set bit of chosen (6-step popcount bisection)
        int pos = 0;
        unsigned long long m64 = chosen;
        int c = __popcll(m64 & 0xFFFFFFFFull);
        if (rr >= c) { pos = 32; rr -= c; m64 >>= 32; }
        unsigned mm = (unsigned)m64;
        c = __popc(mm & 0xFFFFu); if (rr >= c) { pos += 16; rr -= c; mm >>= 16; }
        c = __popc(mm & 0xFFu);   if (rr >= c) { pos += 8;  rr -= c; mm >>= 8; }
        c = __popc(mm & 0xFu);    if (rr >= c) { pos += 4;  rr -= c; mm >>= 4; }
        c = __popc(mm & 0x3u);    if (rr >= c) { pos += 2;  rr -= c; mm >>= 2; }
        c = mm & 1u;              if (rr >= c) { pos += 1; }
        int flat = lo * CHUNK + wordidx * 64 + pos;
        int dd = flat / 9216;           // 96*96
        int rem = flat - dd * 9216;
        int hh = rem / 96;
        int ww = rem - hh * 96;
        px = (float)dd / 95.0f * 2.0f - 1.0f;
        py = (float)hh / 95.0f * 2.0f - 1.0f;
        pz = (float)ww / 95.0f * 2.0f - 1.0f;
    }
    pts[((size_t)b * 3 + 0) * NPTS + p] = px;
    pts[((size_t)b * 3 + 1) * NPTS + p] = py;
    pts[((size_t)b * 3 + 2) * NPTS + p] = pz;
    // fused conv1 GN partial stats
    float s[8] = {}, q[8] = {};
    #pragma unroll
    for (int o = 0; o < 64; o++) {
        float a = sw1[o * 3 + 0] * px + sw1[o * 3 + 1] * py + sw1[o * 3 + 2] * pz;
        s[o >> 3] += a;
        q[o >> 3] += a * a;
    }
    __shared__ float red[4][8][2];
    int wv = threadIdx.x >> 6;
    #pragma unroll
    for (int g = 0; g < 8; g++) {
        float S = s[g], Q = q[g];
        for (int off = 32; off; off >>= 1) {
            S += __shfl_down(S, off, 64);
            Q += __shfl_down(Q, off, 64);
        }
        if ((threadIdx.x & 63) == 0) { red[wv][g][0] = S; red[wv][g][1] = Q; }
    }
    __syncthreads();
    if (threadIdx.x < 8) {
        int g = threadIdx.x;
        float S = red[0][g][0] + red[1][g][0] + red[2][g][0] + red[3][g][0];
        float Q = red[0][g][1] + red[1][g][1] + red[2][g][1] + red[3][g][1];
        float* d = pstat1 + (((size_t)(b * 8 + g)) * 16 + pc) * 2;
        d[0] = S; d[1] = Q;
    }
}

__global__ __launch_bounds__(64) void gn_finalize1(const float* __restrict__ pstat,
                                                   const float* __restrict__ gamma,
                                                   const float* __restrict__ beta,
                                                   float* __restrict__ scale,
                                                   float* __restrict__ shift) {
    int b = blockIdx.x >> 3, g = blockIdx.x & 7;
    const float* base = pstat + (size_t)(b * 8 + g) * 32;
    float S = 0.f, Q = 0.f;
    if (threadIdx.x < 16) { S = base[threadIdx.x * 2]; Q = base[threadIdx.x * 2 + 1]; }
    for (int off = 8; off; off >>= 1) {
        S += __shfl_down(S, off, 64);
        Q += __shfl_down(Q, off, 64);
    }
    __shared__ float ms[2];
    if (threadIdx.x == 0) {
        float inv = 1.0f / (8.0f * 4096.0f);
        float mu = S * inv;
        float var = Q * inv - mu * mu;
        if (var < 0.f) var = 0.f;
        ms[0] = mu; ms[1] = rsqrtf(var + 1e-5f);
    }
    __syncthreads();
    if (threadIdx.x < 8) {
        int c = g * 8 + threadIdx.x;
        float ga = gamma[c] * ms[1];
        scale[b * 64 + c] = ga;
        shift[b * 64 + c] = beta[c] - ms[0] * ga;
    }
}

// ---------------- norm1: recompute conv from pts, norm+ReLU -> A-layout x ----------------
// A-layout: X[p16][cb][lane][e] : p = p16*16+(lane&15), c = cb*32+(lane>>4)*8+e

__global__ __launch_bounds__(256) void norm1(const float* __restrict__ pts,
                                             const float* __restrict__ w1,
                                             const float* __restrict__ scale,
                                             const float* __restrict__ shift,
                                             _Float16* __restrict__ x) {
    int b = blockIdx.x >> 4;
    int pc = blockIdx.x & 15;
    int p = pc * 256 + threadIdx.x;
    __shared__ float sw1[192], ssc[64], ssh[64];
    if (threadIdx.x < 192) sw1[threadIdx.x] = w1[threadIdx.x];
    if (threadIdx.x < 64) {
        ssc[threadIdx.x] = scale[b * 64 + threadIdx.x];
        ssh[threadIdx.x] = shift[b * 64 + threadIdx.x];
    }
    __syncthreads();
    float x0 = pts[((size_t)b * 3 + 0) * NPTS + p];
    float x1 = pts[((size_t)b * 3 + 1) * NPTS + p];
    float x2 = pts[((size_t)b * 3 + 2) * NPTS + p];
    int p16g = (b * NPTS + p) >> 4;
    int pr = p & 15;
    #pragma unroll
    for (int cb = 0; cb < 2; cb++)
        #pragma unroll
        for (int k = 0; k < 4; k++) {
            f16x8 v;
            #pragma unroll
            for (int e = 0; e < 8; e++) {
                int o = cb * 32 + k * 8 + e;
                float a = sw1[o * 3 + 0] * x0 + sw1[o * 3 + 1] * x1 + sw1[o * 3 + 2] * x2;
                v[e] = (_Float16)fmaxf(a * ssc[o] + ssh[o], 0.f);
            }
            *(f16x8*)(x + (((size_t)p16g * 2 + cb) * 64 + k * 16 + pr) * 8) = v;
        }
}

// ---------------- weight cast fp32 -> fp16 fragment layout ----------------
// Wfrag[ob][cb][lane][e] : o = ob*16+(lane&15), c = cb*32+(lane>>4)*8+e

template <int CIN, int COUT>
__global__ __launch_bounds__(256) void cast_w_frag(const float* __restrict__ wf,
                                                   _Float16* __restrict__ wh) {
    constexpr int NCB = CIN / 32;
    constexpr int NCHK = (COUT / 16) * NCB * 64;
    int t = blockIdx.x * 256 + threadIdx.x;
    if (t >= NCHK) return;
    int lane = t & 63;
    int cb = (t >> 6) % NCB;
    int ob = t / (64 * NCB);
    int o = ob * 16 + (lane & 15);
    int c0 = cb * 32 + (lane >> 4) * 8;
    const float* src = wf + (size_t)o * CIN + c0;
    f16x8 v;
    #pragma unroll
    for (int e = 0; e < 8; e++) v[e] = (_Float16)src[e];
    *(f16x8*)(wh + (size_t)t * 8) = v;
}

// ---------------- MFMA GEMM, fragment-native I/O, fused pstat ----------------

template <int CIN, int COUT>
__global__ __launch_bounds__(256) void mfma_gemm(const _Float16* __restrict__ xa,
                                                 const _Float16* __restrict__ wf,
                                                 _Float16* __restrict__ y,
                                                 float* __restrict__ pstat) {
    constexpr int NCB = CIN / 32;
    int b = blockIdx.z;
    int wv = threadIdx.x >> 6;
    int lane = threadIdx.x & 63;
    int lr = lane & 15;
    int lk = lane >> 4;
    int P16 = (b * NPTS + blockIdx.x * 256 + wv * 64) >> 4;
    int O16 = blockIdx.y * 4;
    f32x4 acc[4][4] = {};
    #pragma unroll 2
    for (int cb = 0; cb < NCB; cb++) {
        f16x8 af[4], bf[4];
        #pragma unroll
        for (int i = 0; i < 4; i++)
            af[i] = *(const f16x8*)(xa + (((size_t)(P16 + i) * NCB + cb) * 64 + lane) * 8);
        #pragma unroll
        for (int i = 0; i < 4; i++)
            bf[i] = *(const f16x8*)(wf + (((size_t)(O16 + i) * NCB + cb) * 64 + lane) * 8);
        #pragma unroll
        for (int pf = 0; pf < 4; pf++)
            #pragma unroll
            for (int of = 0; of < 4; of++)
                acc[pf][of] = __builtin_amdgcn_mfma_f32_16x16x32_f16(af[pf], bf[of], acc[pf][of], 0, 0, 0);
    }
    int Pblk = (b * NPTS + blockIdx.x * 256 + wv * 64) >> 6;
    _Float16* yt = y + ((size_t)Pblk * (COUT / 64) + blockIdx.y) * 4096;
    #pragma unroll
    for (int of = 0; of < 4; of++)
        #pragma unroll
        for (int pf = 0; pf < 4; pf++) {
            f16x4 v;
            #pragma unroll
            for (int j = 0; j < 4; j++) v[j] = (_Float16)acc[pf][of][j];
            *(f16x4*)(yt + ((size_t)(of * 4 + pf) * 64 + lane) * 4) = v;
        }
    __shared__ float sred[4][64][2];
    #pragma unroll
    for (int of = 0; of < 4; of++) {
        float S = 0.f, Q = 0.f;
        #pragma unroll
        for (int pf = 0; pf < 4; pf++)
            #pragma unroll
            for (int j = 0; j < 4; j++) {
                float v = acc[pf][of][j];
                S += v; Q += v * v;
            }
        S += __shfl_xor(S, 16, 64); Q += __shfl_xor(Q, 16, 64);
        S += __shfl_xor(S, 32, 64); Q += __shfl_xor(Q, 32, 64);
        if (lk == 0) { sred[wv][of * 16 + lr][0] = S; sred[wv][of * 16 + lr][1] = Q; }
    }
    __syncthreads();
    if (threadIdx.x < 64) {
        int o = threadIdx.x;
        float S = sred[0][o][0] + sred[1][o][0] + sred[2][o][0] + sred[3][o][0];
        float Q = sred[0][o][1] + sred[1][o][1] + sred[2][o][1] + sred[3][o][1];
        float* d = pstat + (((size_t)b * COUT + blockIdx.y * 64 + o) * 16 + blockIdx.x) * 2;
        d[0] = S; d[1] = Q;
    }
}

// ---------------- GN finalize (layers 2,3) ----------------

template <int C>
__global__ __launch_bounds__(256) void gn_finalizeG(const float* __restrict__ pstat,
                                                    const float* __restrict__ gamma,
                                                    const float* __restrict__ beta,
                                                    float* __restrict__ scale,
                                                    float* __restrict__ shift) {
    constexpr int GS = C / 8;
    int b = blockIdx.x >> 3, g = blockIdx.x & 7;
    const float* base = pstat + ((size_t)b * C + g * GS) * 32;
    float S = 0.f, Q = 0.f;
    for (int i = threadIdx.x; i < GS * 16; i += 256) { S += base[2 * i]; Q += base[2 * i + 1]; }
    for (int off = 32; off; off >>= 1) {
        S += __shfl_down(S, off, 64);
        Q += __shfl_down(Q, off, 64);
    }
    __shared__ float ss[8];
    if ((threadIdx.x & 63) == 0) {
        ss[(threadIdx.x >> 6) * 2] = S;
        ss[(threadIdx.x >> 6) * 2 + 1] = Q;
    }
    __syncthreads();
    __shared__ float ms[2];
    if (threadIdx.x == 0) {
        float St = ss[0] + ss[2] + ss[4] + ss[6];
        float Qt = ss[1] + ss[3] + ss[5] + ss[7];
        float inv = 1.0f / ((float)GS * 4096.0f);
        float mu = St * inv;
        float var = Qt * inv - mu * mu;
        if (var < 0.f) var = 0.f;
        ms[0] = mu; ms[1] = rsqrtf(var + 1e-5f);
    }
    __syncthreads();
    for (int i = threadIdx.x; i < GS; i += 256) {
        int c = g * GS + i;
        float ga = gamma[c] * ms[1];
        scale[(size_t)b * C + c] = ga;
        shift[(size_t)b * C + c] = beta[c] - ms[0] * ga;
    }
}

// ---------------- normG: D-native y -> norm+ReLU -> A-layout x (LDS transpose) ----------------

template <int C>
__global__ __launch_bounds__(256) void normG(const _Float16* __restrict__ y,
                                             const float* __restrict__ scale,
                                             const float* __restrict__ shift,
                                             _Float16* __restrict__ x) {
    __shared__ _Float16 sl[64 * C];
    int Pblk = blockIdx.x;
    int b = Pblk >> 6;
    const _Float16* yt = y + (size_t)Pblk * 64 * C;
    constexpr int NCH = 64 * C / 4;      // f16x4 chunks per tile
    for (int q = threadIdx.x; q < NCH; q += 256) {
        int lane = q & 63;
        int pf = (q >> 6) & 3;
        int of = (q >> 8) & 3;
        int Ob = q >> 10;
        int o = Ob * 64 + of * 16 + (lane & 15);
        int pbase = pf * 16 + (lane >> 4) * 4;
        f16x4 v = *(const f16x4*)(yt + (size_t)q * 4);
        float sc = scale[(size_t)b * C + o];
        float sh = shift[(size_t)b * C + o];
        int ch = o >> 3;
        #pragma unroll
        for (int e = 0; e < 4; e++) {
            int p = pbase + e;
            float r = fmaxf((float)v[e] * sc + sh, 0.f);
            sl[p * C + ((ch ^ (p & 7)) << 3) + (o & 7)] = (_Float16)r;
        }
    }
    __syncthreads();
    int wv = threadIdx.x >> 6;
    int lane = threadIdx.x & 63;
    int p = wv * 16 + (lane & 15);
    int k = lane >> 4;
    int P16 = Pblk * 4 + wv;
    #pragma unroll
    for (int cb = 0; cb < C / 32; cb++) {
        int ch = cb * 4 + k;
        f16x8 v = *(const f16x8*)(sl + p * C + ((ch ^ (p & 7)) << 3));
        *(f16x8*)(x + (((size_t)P16 * (C / 32) + cb) * 64 + lane) * 8) = v;
    }
}

// ---------------- layer 4: GEMM with pooled epilogue (no y materialization) ----------------

__global__ __launch_bounds__(256) void mfma_gemm_pool(const _Float16* __restrict__ xa,
                                                      const _Float16* __restrict__ wf,
                                                      float* __restrict__ pstat4) {
    constexpr int CIN = 256, NCB = CIN / 32;
    int b = blockIdx.z;
    int wv = threadIdx.x >> 6;
    int lane = threadIdx.x & 63;
    int lr = lane & 15;
    int lk = lane >> 4;
    int P16 = (b * NPTS + blockIdx.x * 256 + wv * 64) >> 4;
    int O16 = blockIdx.y * 4;
    f32x4 acc[4][4] = {};
    #pragma unroll 2
    for (int cb = 0; cb < NCB; cb++) {
        f16x8 af[4], bf[4];
        #pragma unroll
        for (int i = 0; i < 4; i++)
            af[i] = *(const f16x8*)(xa + (((size_t)(P16 + i) * NCB + cb) * 64 + lane) * 8);
        #pragma unroll
        for (int i = 0; i < 4; i++)
            bf[i] = *(const f16x8*)(wf + (((size_t)(O16 + i) * NCB + cb) * 64 + lane) * 8);
        #pragma unroll
        for (int pf = 0; pf < 4; pf++)
            #pragma unroll
            for (int of = 0; of < 4; of++)
                acc[pf][of] = __builtin_amdgcn_mfma_f32_16x16x32_f16(af[pf], bf[of], acc[pf][of], 0, 0, 0);
    }
    __shared__ float sred[4][64][4];
    #pragma unroll
    for (int of = 0; of < 4; of++) {
        float S = 0.f, Q = 0.f, MX = -1e30f, MN = 1e30f;
        #pragma unroll
        for (int pf = 0; pf < 4; pf++)
            #pragma unroll
            for (int j = 0; j < 4; j++) {
                float v = acc[pf][of][j];
                S += v; Q += v * v;
                MX = fmaxf(MX, v); MN = fminf(MN, v);
            }
        S += __shfl_xor(S, 16, 64); Q += __shfl_xor(Q, 16, 64);
        MX = fmaxf(MX, __shfl_xor(MX, 16, 64)); MN = fminf(MN, __shfl_xor(MN, 16, 64));
        S += __shfl_xor(S, 32, 64); Q += __shfl_xor(Q, 32, 64);
        MX = fmaxf(MX, __shfl_xor(MX, 32, 64)); MN = fminf(MN, __shfl_xor(MN, 32, 64));
        if (lk == 0) {
            sred[wv][of * 16 + lr][0] = S;
            sred[wv][of * 16 + lr][1] = Q;
            sred[wv][of * 16 + lr][2] = MX;
            sred[wv][of * 16 + lr][3] = MN;
        }
    }
    __syncthreads();
    if (threadIdx.x < 64) {
        int o = threadIdx.x;
        float S = sred[0][o][0] + sred[1][o][0] + sred[2][o][0] + sred[3][o][0];
        float Q = sred[0][o][1] + sred[1][o][1] + sred[2][o][1] + sred[3][o][1];
        float MX = fmaxf(fmaxf(sred[0][o][2], sred[1][o][2]), fmaxf(sred[2][o][2], sred[3][o][2]));
        float MN = fminf(fminf(sred[0][o][3], sred[1][o][3]), fminf(sred[2][o][3], sred[3][o][3]));
        *(float4*)(pstat4 + (((size_t)b * 512 + blockIdx.y * 64 + o) * 16 + blockIdx.x) * 4) =
            make_float4(S, Q, MX, MN);
    }
}

// ---------------- pool finalize ----------------

__global__ __launch_bounds__(256) void pool_final(const float* __restrict__ pstat4,
                                                  const float* __restrict__ gamma,
                                                  const float* __restrict__ beta,
                                                  float* __restrict__ g) {
    int b = blockIdx.x;
    __shared__ float sS[512], sQ[512];
    __shared__ float ms[8][2];
    float Sa[2], Qa[2], MXa[2], MNa[2];
    #pragma unroll
    for (int h = 0; h < 2; h++) {
        int o = threadIdx.x + h * 256;
        float S = 0.f, Q = 0.f, MX = -1e30f, MN = 1e30f;
        for (int pb = 0; pb < 16; pb++) {
            float4 v = *(const float4*)(pstat4 + (((size_t)b * 512 + o) * 16 + pb) * 4);
            S += v.x; Q += v.y; MX = fmaxf(MX, v.z); MN = fminf(MN, v.w);
        }
        Sa[h] = S; Qa[h] = Q; MXa[h] = MX; MNa[h] = MN;
        sS[o] = S; sQ[o] = Q;
    }
    __syncthreads();
    if (threadIdx.x < 8) {
        int gr = threadIdx.x;
        float St = 0.f, Qt = 0.f;
        for (int i = 0; i < 64; i++) { St += sS[gr * 64 + i]; Qt += sQ[gr * 64 + i]; }
        float inv = 1.0f / (64.0f * 4096.0f);
        float mu = St * inv;
        float var = Qt * inv - mu * mu;
        if (var < 0.f) var = 0.f;
        ms[gr][0] = mu; ms[gr][1] = rsqrtf(var + 1e-5f);
    }
    __syncthreads();
    #pragma unroll
    for (int h = 0; h < 2; h++) {
        int o = threadIdx.x + h * 256;
        int gr = o >> 6;
        float sc = gamma[o] * ms[gr][1];
        float sh = beta[o] - ms[gr][0] * sc;
        float m = (sc >= 0.f ? MXa[h] : MNa[h]) * sc + sh;
        g[b * 512 + o] = fmaxf(m, 0.f);
    }
}

// ---------------- FC head ----------------

__global__ __launch_bounds__(128) void head_kernel(const float* __restrict__ g,
                                                   const float* __restrict__ fc1w,
                                                   const float* __restrict__ fc1b,
                                                   const float* __restrict__ fc2w,
                                                   const float* __restrict__ fc2b,
                                                   float* __restrict__ out) {
    int b = blockIdx.x;
    int o = threadIdx.x;   // 128
    __shared__ float sg[512];
    for (int i = threadIdx.x; i < 512; i += 128) sg[i] = g[b * 512 + i];
    __syncthreads();
    float acc = fc1b[o];
    for (int c = 0; c < 512; c++) acc += sg[c] * fc1w[o * 512 + c];
    float h = fmaxf(acc, 0.f) * fc2w[o];
    for (int off = 32; off; off >>= 1) h += __shfl_down(h, off, 64);
    __shared__ float s2[2];
    if ((threadIdx.x & 63) == 0) s2[threadIdx.x >> 6] = h;
    __syncthreads();
    if (threadIdx.x == 0) out[b] = s2[0] + s2[1] + fc2b[0];
}

// ---------------- launch ----------------

extern "C" void kernel_launch(void* const* d_in, const int* in_sizes, int n_in,
                              void* d_out, int out_size, void* d_ws, size_t ws_size,
                              hipStream_t stream) {
    const float* vol  = (const float*)d_in[0];
    const float* w1   = (const float*)d_in[1];
    const float* gn1w = (const float*)d_in[2];
    const float* gn1b = (const float*)d_in[3];
    const float* w2   = (const float*)d_in[4];
    const float* gn2w = (const float*)d_in[5];
    const float* gn2b = (const float*)d_in[6];
    const float* w3   = (const float*)d_in[7];
    const float* gn3w = (const float*)d_in[8];
    const float* gn3b = (const float*)d_in[9];
    const float* w4   = (const float*)d_in[10];
    const float* gn4w = (const float*)d_in[11];
    const float* gn4b = (const float*)d_in[12];
    const float* fc1w = (const float*)d_in[13];
    const float* fc1b = (const float*)d_in[14];
    const float* fc2w = (const float*)d_in[15];
    const float* fc2b = (const float*)d_in[16];
    float* out = (float*)d_out;

    char* ws = (char*)d_ws;
    size_t cur = 0;
    auto alloc = [&](size_t bytes) -> void* {
        cur = (cur + 255) & ~(size_t)255;
        void* p = ws + cur;
        cur += bytes;
        return p;
    };
    int*      counts  = (int*)alloc((size_t)NB * NCHUNK * 4);
    int*      prefix  = (int*)alloc((size_t)NB * NCHUNK * 4);
    int*      totals  = (int*)alloc(64);
    unsigned long long* bits = (unsigned long long*)alloc((size_t)NB * NCHUNK * 16 * 8);
    float*    pts     = (float*)alloc((size_t)NB * 3 * NPTS * 4);
    float*    gbuf    = (float*)alloc((size_t)NB * 512 * 4);
    float*    pstat1  = (float*)alloc((size_t)NB * 8 * 16 * 2 * 4);
    float*    pstatG  = (float*)alloc((size_t)NB * 512 * 16 * 2 * 4);
    float*    pstat4  = (float*)alloc((size_t)NB * 512 * 16 * 4 * 4);
    float*    scale   = (float*)alloc((size_t)NB * 512 * 4);
    float*    shift   = (float*)alloc((size_t)NB * 512 * 4);
    _Float16* w2f     = (_Float16*)alloc((size_t)128 * 64 * 2);
    _Float16* w3f     = (_Float16*)alloc((size_t)256 * 128 * 2);
    _Float16* w4f     = (_Float16*)alloc((size_t)512 * 256 * 2);
    _Float16* x1      = (_Float16*)alloc((size_t)NB * NPTS * 64 * 2);
    _Float16* y2      = (_Float16*)alloc((size_t)NB * NPTS * 128 * 2);
    _Float16* x2      = (_Float16*)alloc((size_t)NB * NPTS * 128 * 2);
    _Float16* y3      = (_Float16*)alloc((size_t)NB * NPTS * 256 * 2);
    _Float16* x3      = (_Float16*)alloc((size_t)NB * NPTS * 256 * 2);

    // 1. mask/count/scan, then points + fused conv1 stats
    count_kernel<<<dim3(NB * NCHUNK), dim3(256), 0, stream>>>(vol, counts, bits);
    scan_kernel<<<dim3(NB), dim3(1024), 0, stream>>>(counts, prefix, totals);
    points_kernel<<<dim3(NB * 16), dim3(256), 0, stream>>>(bits, prefix, totals, w1, pts, pstat1);

    // 2. weight casts to fragment layout
    cast_w_frag<64, 128><<<dim3(4), dim3(256), 0, stream>>>(w2, w2f);
    cast_w_frag<128, 256><<<dim3(16), dim3(256), 0, stream>>>(w3, w3f);
    cast_w_frag<256, 512><<<dim3(64), dim3(256), 0, stream>>>(w4, w4f);

    // 3. layer 1 finalize + norm (recompute conv)
    gn_finalize1<<<dim3(NB * 8), dim3(64), 0, stream>>>(pstat1, gn1w, gn1b, scale, shift);
    norm1<<<dim3(NB * 16), dim3(256), 0, stream>>>(pts, w1, scale, shift, x1);

    // 4. layer 2: 64 -> 128
    mfma_gemm<64, 128><<<dim3(16, 2, NB), dim3(256), 0, stream>>>(x1, w2f, y2, pstatG);
    gn_finalizeG<128><<<dim3(NB * 8), dim3(256), 0, stream>>>(pstatG, gn2w, gn2b, scale, shift);
    normG<128><<<dim3(NB * 64), dim3(256), 0, stream>>>(y2, scale, shift, x2);

    // 5. layer 3: 128 -> 256
    mfma_gemm<128, 256><<<dim3(16, 4, NB), dim3(256), 0, stream>>>(x2, w3f, y3, pstatG);
    gn_finalizeG<256><<<dim3(NB * 8), dim3(256), 0, stream>>>(pstatG, gn3w, gn3b, scale, shift);
    normG<256><<<dim3(NB * 64), dim3(256), 0, stream>>>(y3, scale, shift, x3);

    // 6. layer 4: 256 -> 512 with pooled epilogue, then finalize
    mfma_gemm_pool<<<dim3(16, 8, NB), dim3(256), 0, stream>>>(x3, w4f, pstat4);
    pool_final<<<dim3(NB), dim3(256), 0, stream>>>(pstat4, gn4w, gn4b, gbuf);

    // 7. head
    head_kernel<<<dim3(NB), dim3(128), 0, stream>>>(gbuf, fc1w, fc1b, fc2w, fc2b, out);
}